// Round 15
// baseline (1050.620 us; speedup 1.0000x reference)
//
#include <hip/hip_runtime.h>
#include <cstddef>

// ---------------------------------------------------------------------------
// ChebNet MFMA bf16: B=32, N=1024, layers 6->128->512->1024 (K=3), maxpool,
// FC 1024->512->128->40. BCv=32 x 1 chunk (~241 MB ws) when ws allows,
// else 16 x 2, else 8 x 4.
// NO fp32 inter-layer activations: proj writes relu(out) directly as hi/lo
// bf16 split; prep2 "lite" mode for layers 2/3. 5 rotating SLv slots.
// init: single kernel = zero(pool) + wconvT x3.
// adj: SYMMETRIC upper-triangle tiles (36/64); reg-staged LDS dbuf; epi v3
//   (both tile layouts via swizzled LDS -> coalesced uint4 stores).
// lx: 128f x 128n tile (2x2 waves, acc[4][4], 16 MFMA/step/wave), gld_lds
//   staging, TRIPLE-buffered, counted vmcnt(4). 48KB LDS -> 3 blocks/CU.
// proj: 256r x 128g tile, 8 waves (512 thr), gld_lds, 3 bufs, vmcnt(3).
// fc: single fused kernel (1 block/sample, f1/f2 in LDS).
// 1D grids, XCD-aware decode (sample = L & (BC-1)).
// ---------------------------------------------------------------------------

#define NN 1024

typedef unsigned short ushort_t;
typedef __bf16 bf16x8 __attribute__((ext_vector_type(8)));
typedef float f32x4 __attribute__((ext_vector_type(4)));

__device__ inline ushort_t f2bf(float f) {
    unsigned int u = __float_as_uint(f);
    u = (u + 0x7fffu + ((u >> 16) & 1u)) >> 16;
    return (ushort_t)u;
}
__device__ inline float bf2f(ushort_t s) {
    return __uint_as_float(((unsigned int)s) << 16);
}

// Async global->LDS, 16B per lane. LDS dest is wave-uniform base; HW writes
// lane l at base + l*16B -> 16 rows x 32 ushorts per instruction,
// lane l -> row (l>>2), col (l&3)*8.
__device__ __attribute__((always_inline)) inline void gld16(
    const ushort_t* g, ushort_t* l) {
    __builtin_amdgcn_global_load_lds(
        (__attribute__((address_space(1))) void*)(ushort_t*)g,
        (__attribute__((address_space(3))) void*)l, 16, 0, 0);
}

// init: blocks [0,16): zero pool; rest: wconvT for W1/W2/W3.
// W[p][Fi][Fo] fp32 -> Wt[p][Fo][Ks] bf16, LDS-tiled transpose, zero-pad K.
__global__ __launch_bounds__(256) void init_kernel(
    const float* __restrict__ W1, const float* __restrict__ W2,
    const float* __restrict__ W3, ushort_t* __restrict__ Wt,
    float* __restrict__ pool) {
    __shared__ float T[64][65];
    int bid = blockIdx.x, t = threadIdx.x;
    if (bid < 16) {
#pragma unroll
        for (int k = 0; k < 8; ++k) pool[bid * 2048 + k * 256 + t] = 0.f;
        return;
    }
    bid -= 16;
    const float* W; ushort_t* wt; int Fi, Fo, Ks, gx, gy, p;
    if (bid < 6)       { W = W1; wt = Wt;          Fi = 6;   Fo = 128;  Ks = 32;
                         gx = bid % 2; gy = 0; p = bid / 2; }
    else if (bid < 54) { int b = bid - 6;  W = W2; wt = Wt + 12288;  Fi = 128; Fo = 512;  Ks = 128;
                         gx = b % 8; gy = (b / 8) % 2; p = b / 16; }
    else               { int b = bid - 54; W = W3; wt = Wt + 208896; Fi = 512; Fo = 1024; Ks = 512;
                         gx = b % 16; gy = (b / 16) % 8; p = b / 128; }
    int k0 = gy * 64, g0 = gx * 64;
#pragma unroll
    for (int q = 0; q < 16; ++q) {
        int kr = (t >> 6) + 4 * q, gc = t & 63;
        int k = k0 + kr, g = g0 + gc;
        T[kr][gc] = (k < Fi && g < Fo) ? W[((size_t)p * Fi + k) * Fo + g] : 0.f;
    }
    __syncthreads();
#pragma unroll
    for (int q = 0; q < 16; ++q) {
        int gr = (t >> 6) + 4 * q, kc = t & 63;
        int g = g0 + gr, k = k0 + kc;
        if (g < Fo && k < Ks)
            wt[((size_t)p * Fo + g) * Ks + k] = f2bf(T[kc][gr]);
    }
}

// Full mode (X != null): read fp32 X, write hi/lo split + Xt + sq.
// Lite mode (X == null): read existing hi/lo (x = hi+lo), write only Xt + sq.
__global__ __launch_bounds__(256) void prep2_kernel(
    const float* __restrict__ X, ushort_t* __restrict__ hi, ushort_t* __restrict__ lo,
    ushort_t* __restrict__ Xt, float* __restrict__ sq, int F, int Fp, int bsh) {
    int L = blockIdx.x;
    int b = L & ((1 << bsh) - 1), n0 = (L >> bsh) * 64;
    int t = threadIdx.x;
    __shared__ float T[64][65];
    __shared__ float red[4][64];
    const float* Xb = X ? (X + ((size_t)b * NN + n0) * F) : nullptr;
    const ushort_t* hb = hi + ((size_t)b * NN + n0) * Fp;
    const ushort_t* lb = lo + ((size_t)b * NN + n0) * Fp;
    float sacc = 0.f;

    for (int f0 = 0; f0 < Fp; f0 += 64) {
        __syncthreads();
#pragma unroll
        for (int p = 0; p < 16; ++p) {
            int nr = (t >> 6) + 4 * p, fc = t & 63;
            int f = f0 + fc;
            float xv = 0.f;
            if (f < F) {
                if (Xb) xv = Xb[(size_t)nr * F + f];
                else {
                    size_t off = (size_t)nr * Fp + f;
                    xv = bf2f(hb[off]) + bf2f(lb[off]);
                }
            }
            T[nr][fc] = xv;
        }
        __syncthreads();
        if (Xb) {
#pragma unroll
            for (int p = 0; p < 16; ++p) {
                int nr = (t >> 6) + 4 * p, fc = t & 63;
                int f = f0 + fc;
                if (f < Fp) {
                    float x = T[nr][fc];
                    ushort_t h = f2bf(x);
                    size_t off = ((size_t)b * NN + n0 + nr) * Fp + f;
                    hi[off] = h;
                    lo[off] = f2bf(x - bf2f(h));
                }
            }
        }
#pragma unroll
        for (int p = 0; p < 16; ++p) {
            int fr = (t >> 6) + 4 * p;
            int f = f0 + fr;
            if (f < F)
                Xt[((size_t)b * Fp + f) * NN + n0 + (t & 63)] = f2bf(T[t & 63][fr]);
        }
        {
            int nl = t & 63, fq = t >> 6;
#pragma unroll
            for (int fc = 0; fc < 16; ++fc) {
                float v = T[nl][fq * 16 + fc];
                sacc += v * v;
            }
        }
    }
    red[t >> 6][t & 63] = sacc;
    __syncthreads();
    if (t < 64)
        sq[(size_t)b * NN + n0 + t] = red[0][t] + red[1][t] + red[2][t] + red[3][t];
}

// A[b,n,m] = exp(2 x_n.x_m - sq_n - sq_m) -> bf16 (split hi/lo MFMA), dbuf;
// reg-staged (proven). SYMMETRIC: upper triangle only (ti<=tj).
// Epilogue v3: exp pass -> two swizzled LDS layouts -> coalesced uint4 stores.
// deg partials: row-sums -> slot tj*2+(wave&1), col-sums -> slot ti*2+(wave>>1).
__global__ __launch_bounds__(256) void adj_kernel(
    const ushort_t* __restrict__ hi, const ushort_t* __restrict__ lo,
    const float* __restrict__ sq, ushort_t* __restrict__ Abf,
    float* __restrict__ deg_part, int Fp, int bsh, int BCv) {
    int t = threadIdx.x;
    int L = blockIdx.x;
    int b = L & ((1 << bsh) - 1);
    int rest = L >> bsh;          // [0,36): triangular tile index
    int ti = 0;
    while (rest >= 8 - ti) { rest -= 8 - ti; ++ti; }
    int tj = ti + rest;
    int n0 = ti * 128, m0 = tj * 128;
    const ushort_t* Hb = hi + (size_t)b * NN * Fp;
    const ushort_t* Lb = lo + (size_t)b * NN * Fp;
    ushort_t* Ab = Abf + (size_t)b * NN * NN;
    const float* sqb = sq + (size_t)b * NN;

    int lane = t & 63, quad = lane >> 4, l16 = lane & 15, wave = t >> 6;
    int rowoff = (wave >> 1) * 64, coloff = (wave & 1) * 64;

    __shared__ __align__(16) ushort_t smem[40960];

    f32x4 acc[4][4];
#pragma unroll
    for (int i = 0; i < 4; ++i)
#pragma unroll
        for (int j = 0; j < 4; ++j) acc[i][j] = (f32x4){0.f, 0.f, 0.f, 0.f};

    int rr0 = t >> 2, kq = (t & 3) * 8;
    int rr1 = rr0 + 64;
    const ushort_t* pAh0 = Hb + (size_t)(n0 + rr0) * Fp + kq;
    const ushort_t* pAh1 = Hb + (size_t)(n0 + rr1) * Fp + kq;
    const ushort_t* pAl0 = Lb + (size_t)(n0 + rr0) * Fp + kq;
    const ushort_t* pAl1 = Lb + (size_t)(n0 + rr1) * Fp + kq;
    const ushort_t* pBh0 = Hb + (size_t)(m0 + rr0) * Fp + kq;
    const ushort_t* pBh1 = Hb + (size_t)(m0 + rr1) * Fp + kq;
    const ushort_t* pBl0 = Lb + (size_t)(m0 + rr0) * Fp + kq;
    const ushort_t* pBl1 = Lb + (size_t)(m0 + rr1) * Fp + kq;
    int o0 = rr0 * 40 + kq, o1 = rr1 * 40 + kq;

    {
        *(uint4*)&smem[o0]         = *(const uint4*)pAh0;
        *(uint4*)&smem[o1]         = *(const uint4*)pAh1;
        *(uint4*)&smem[5120 + o0]  = *(const uint4*)pAl0;
        *(uint4*)&smem[5120 + o1]  = *(const uint4*)pAl1;
        *(uint4*)&smem[10240 + o0] = *(const uint4*)pBh0;
        *(uint4*)&smem[10240 + o1] = *(const uint4*)pBh1;
        *(uint4*)&smem[15360 + o0] = *(const uint4*)pBl0;
        *(uint4*)&smem[15360 + o1] = *(const uint4*)pBl1;
    }
    __syncthreads();

    int NIT = Fp >> 5;
    for (int it = 0; it < NIT; ++it) {
        int cur = (it & 1) * 20480;
        int nxt = 20480 - cur;
        uint4 rh0, rh1, rl0, rl1, sh0, sh1, sl0, sl1;
        if (it + 1 < NIT) {
            int k = (it + 1) * 32;
            rh0 = *(const uint4*)(pAh0 + k); rh1 = *(const uint4*)(pAh1 + k);
            rl0 = *(const uint4*)(pAl0 + k); rl1 = *(const uint4*)(pAl1 + k);
            sh0 = *(const uint4*)(pBh0 + k); sh1 = *(const uint4*)(pBh1 + k);
            sl0 = *(const uint4*)(pBl0 + k); sl1 = *(const uint4*)(pBl1 + k);
        }
        ushort_t* Ah = smem + cur;
        ushort_t* Al = smem + cur + 5120;
        ushort_t* Bh = smem + cur + 10240;
        ushort_t* Bl = smem + cur + 15360;
        bf16x8 ah[4], al[4], bh[4], bl[4];
#pragma unroll
        for (int i = 0; i < 4; ++i) {
            ah[i] = *(const bf16x8*)&Ah[(rowoff + i * 16 + l16) * 40 + quad * 8];
            al[i] = *(const bf16x8*)&Al[(rowoff + i * 16 + l16) * 40 + quad * 8];
        }
#pragma unroll
        for (int j = 0; j < 4; ++j) {
            bh[j] = *(const bf16x8*)&Bh[(coloff + j * 16 + l16) * 40 + quad * 8];
            bl[j] = *(const bf16x8*)&Bl[(coloff + j * 16 + l16) * 40 + quad * 8];
        }
#pragma unroll
        for (int i = 0; i < 4; ++i)
#pragma unroll
            for (int j = 0; j < 4; ++j) {
                acc[i][j] = __builtin_amdgcn_mfma_f32_16x16x32_bf16(al[i], bh[j], acc[i][j], 0, 0, 0);
                acc[i][j] = __builtin_amdgcn_mfma_f32_16x16x32_bf16(ah[i], bl[j], acc[i][j], 0, 0, 0);
                acc[i][j] = __builtin_amdgcn_mfma_f32_16x16x32_bf16(ah[i], bh[j], acc[i][j], 0, 0, 0);
            }
        if (it + 1 < NIT) {
            *(uint4*)&smem[nxt + o0]         = rh0;
            *(uint4*)&smem[nxt + o1]         = rh1;
            *(uint4*)&smem[nxt + 5120 + o0]  = rl0;
            *(uint4*)&smem[nxt + 5120 + o1]  = rl1;
            *(uint4*)&smem[nxt + 10240 + o0] = sh0;
            *(uint4*)&smem[nxt + 10240 + o1] = sh1;
            *(uint4*)&smem[nxt + 15360 + o0] = sl0;
            *(uint4*)&smem[nxt + 15360 + o1] = sl1;
        }
        __syncthreads();
    }

    bool offdiag = (ti != tj);
    float rs[4][4];
    float cs[4] = {0.f, 0.f, 0.f, 0.f};
#pragma unroll
    for (int i = 0; i < 4; ++i)
#pragma unroll
        for (int r = 0; r < 4; ++r) rs[i][r] = 0.f;

    // exp pass: deg sums + BOTH tile layouts into swizzled LDS
#pragma unroll
    for (int j = 0; j < 4; ++j) {
        int ml = coloff + j * 16 + l16;
        float sm = sqb[m0 + ml];
#pragma unroll
        for (int i = 0; i < 4; ++i) {
#pragma unroll
            for (int r = 0; r < 4; ++r) {
                int nl = rowoff + i * 16 + quad * 4 + r;
                float v = __expf(2.f * acc[i][j][r] - sqb[n0 + nl] - sm);
                rs[i][r] += v;
                ushort_t vb = f2bf(v);
                smem[nl * 128 + (((ml >> 3) ^ (nl & 7)) << 3) + (ml & 7)] = vb;
                if (offdiag) {
                    cs[j] += v;
                    smem[16384 + ml * 128 + (((nl >> 3) ^ (ml & 7)) << 3) + (nl & 7)] = vb;
                }
            }
        }
    }
    __syncthreads();
    // direct tile write, coalesced
    for (int s2 = t; s2 < 2048; s2 += 256) {
        int nl = s2 >> 4, oct = s2 & 15;
        uint4 v4 = *(const uint4*)&smem[nl * 128 + ((oct ^ (nl & 7)) << 3)];
        *(uint4*)(Ab + (size_t)(n0 + nl) * NN + m0 + oct * 8) = v4;
    }

    int slot = tj * 2 + (wave & 1);
#pragma unroll
    for (int i = 0; i < 4; ++i)
#pragma unroll
        for (int r = 0; r < 4; ++r) {
            float s = rs[i][r];
            s += __shfl_xor(s, 1);
            s += __shfl_xor(s, 2);
            s += __shfl_xor(s, 4);
            s += __shfl_xor(s, 8);
            if (l16 == 0)
                deg_part[((size_t)slot * BCv + b) * NN + n0 + rowoff + i * 16 + quad * 4 + r] = s;
        }

    if (offdiag) {
        // column sums -> mirror rows' partials: slot ti*2 + (wave>>1)
#pragma unroll
        for (int j = 0; j < 4; ++j) {
            float s = cs[j];
            s += __shfl_xor(s, 16);
            s += __shfl_xor(s, 32);
            cs[j] = s;
        }
        if (quad == 0) {
#pragma unroll
            for (int j = 0; j < 4; ++j)
                deg_part[((size_t)(ti * 2 + (wave >> 1)) * BCv + b) * NN +
                         m0 + coloff + j * 16 + l16] = cs[j];
        }
        // mirrored tile write, coalesced (layout 2 written pre-sync above)
        for (int s2 = t; s2 < 2048; s2 += 256) {
            int ml = s2 >> 4, oct = s2 & 15;
            uint4 v4 = *(const uint4*)&smem[16384 + ml * 128 + ((oct ^ (ml & 7)) << 3)];
            *(uint4*)(Ab + (size_t)(m0 + ml) * NN + n0 + oct * 8) = v4;
        }
    }
}

// dis[b][n] = rsqrt(sum of 16 deg partials); Xt[b][f][n0..] *= dis[n] in place.
__global__ __launch_bounds__(256) void disscale_kernel(
    ushort_t* __restrict__ Xt, const float* __restrict__ deg_part,
    float* __restrict__ dis, int Fp, int bsh, int BCv) {
    int L = blockIdx.x;
    int b = L & ((1 << bsh) - 1), n0 = (L >> bsh) * 64;
    int t = threadIdx.x;
    __shared__ float dloc[64];
    if (t < 64) {
        float s = 0.f;
#pragma unroll
        for (int k = 0; k < 16; ++k) s += deg_part[((size_t)k * BCv + b) * NN + n0 + t];
        float d = rsqrtf(s);
        dloc[t] = d;
        dis[(size_t)b * NN + n0 + t] = d;
    }
    __syncthreads();
    int lane = t & 63, fq = t >> 6;
    float d = dloc[lane];
    ushort_t* Xb = Xt + (size_t)b * Fp * NN + n0 + lane;
    for (int f = fq; f < Fp; f += 4) {
        size_t off = (size_t)f * NN;
        Xb[off] = f2bf(bf2f(Xb[off]) * d);
    }
}

// lx: acc[f][n] = sum_k in_t[f][k] * A[n][k]  (A raw symmetric).
// Tile 128f x 128n, 4 waves (2x2: rowoff=(w>>1)*64, coloff=(w&1)*64),
// acc[4][4], K=1024 in 32 steps. gld_lds staging, TRIPLE-buffered (depth-2),
// raw s_barrier + counted vmcnt(4). 48KB LDS -> 3 blocks/CU.
// mode0: out_t = xin - dn^2*acc; out_b = inv*xin - dn*acc.
// mode1: out_b = inv*(2*xin - x0) - 2*dn*acc.
__global__ __launch_bounds__(256) void lx_kernel(
    const ushort_t* __restrict__ Abf, const float* __restrict__ dis,
    const ushort_t* __restrict__ in_t, const ushort_t* __restrict__ x0t,
    ushort_t* __restrict__ out_t, ushort_t* __restrict__ out_b,
    int F, int Fp, int mode, int ft, int bsh) {
    int t = threadIdx.x;
    int L = blockIdx.x;
    int b = L & ((1 << bsh) - 1);
    int rest = L >> bsh;
    int m0 = (rest % ft) * 128;   // f tile (128)
    int n0 = (rest / ft) * 128;   // n tile (128)
    const ushort_t* Ain = in_t + (size_t)b * Fp * NN;
    const ushort_t* Ab = Abf + (size_t)b * NN * NN;

    int lane = t & 63, quad = lane >> 4, l16 = lane & 15, wave = t >> 6;
    int rowoff = (wave >> 1) * 64, coloff = (wave & 1) * 64;

    __shared__ __align__(16) ushort_t smem[24576];   // 3 x (A[128][32] + B[128][32])

    f32x4 acc[4][4];
#pragma unroll
    for (int i = 0; i < 4; ++i)
#pragma unroll
        for (int j = 0; j < 4; ++j) acc[i][j] = (f32x4){0.f, 0.f, 0.f, 0.f};

    int lr = lane >> 2, lk = (lane & 3) * 8;
    const ushort_t* gA = Ain + (size_t)(m0 + wave * 32 + lr) * NN + lk;
    const ushort_t* gB = Ab + (size_t)(n0 + wave * 32 + lr) * NN + lk;

#define LX_STAGE(BOFF, CI)                                            \
    {                                                                 \
        int k_ = (CI) * 32;                                           \
        ushort_t* As_ = smem + (BOFF) + wave * 1024;                  \
        ushort_t* Bs_ = smem + (BOFF) + 4096 + wave * 1024;           \
        gld16(gA + k_, As_);                                          \
        gld16(gA + (size_t)16 * NN + k_, As_ + 512);                  \
        gld16(gB + k_, Bs_);                                          \
        gld16(gB + (size_t)16 * NN + k_, Bs_ + 512);                  \
    }
#define LX_COMP(BOFF)                                                            \
    {                                                                            \
        ushort_t* As_ = smem + (BOFF);                                           \
        ushort_t* Bs_ = As_ + 4096;                                              \
        bf16x8 af[4], bfv[4];                                                    \
        _Pragma("unroll")                                                        \
        for (int i = 0; i < 4; ++i)                                              \
            af[i] = *(const bf16x8*)&As_[(rowoff + i * 16 + l16) * 32 + quad * 8]; \
        _Pragma("unroll")                                                        \
        for (int j = 0; j < 4; ++j)                                              \
            bfv[j] = *(const bf16x8*)&Bs_[(coloff + j * 16 + l16) * 32 + quad * 8]; \
        _Pragma("unroll")                                                        \
        for (int i = 0; i < 4; ++i)                                              \
            _Pragma("unroll")                                                    \
            for (int j = 0; j < 4; ++j)                                          \
                acc[i][j] = __builtin_amdgcn_mfma_f32_16x16x32_bf16(af[i], bfv[j], acc[i][j], 0, 0, 0); \
    }

    LX_STAGE(0, 0);
    LX_STAGE(8192, 1);
    int cur = 0;
    for (int ci = 0; ci < 32; ++ci) {
        if (ci < 31) { asm volatile("s_waitcnt vmcnt(4)" ::: "memory"); }
        else         { asm volatile("s_waitcnt vmcnt(0)" ::: "memory"); }
        __builtin_amdgcn_s_barrier();
        asm volatile("" ::: "memory");
        if (ci + 2 < 32) {
            int noff = cur + 16384; if (noff >= 24576) noff -= 24576;
            LX_STAGE(noff, ci + 2);
        }
        LX_COMP(cur);
        cur += 8192; if (cur >= 24576) cur = 0;
    }
#undef LX_STAGE
#undef LX_COMP
    __syncthreads();   // all waves done reading stage bufs before epilogue reuse

#pragma unroll
    for (int j = 0; j < 4; ++j) {
        int nl = coloff + j * 16 + l16;
        int n = n0 + nl;
        float dn = dis[(size_t)b * NN + n];
        float inv = 1.f / dn;
        float dn2 = dn * dn;
#pragma unroll
        for (int i = 0; i < 4; ++i) {
#pragma unroll
            for (int r = 0; r < 4; ++r) {
                int fl = rowoff + i * 16 + quad * 4 + r;
                int f = m0 + fl;
                float o = 0.f;
                if (f < F) {
                    float a = acc[i][j][r];
                    size_t off = (size_t)f * NN + n;
                    float xin = bf2f(Ain[off]);
                    if (mode == 0) {
                        out_t[(size_t)b * Fp * NN + off] = f2bf(xin - dn2 * a);
                        o = inv * xin - dn * a;
                    } else {
                        float x0 = bf2f(x0t[(size_t)b * Fp * NN + off]);
                        o = inv * (2.f * xin - x0) - 2.f * dn * a;
                    }
                }
                smem[nl * 128 + (((fl >> 3) ^ (nl & 7)) << 3) + (fl & 7)] = f2bf(o);
            }
        }
    }
    __syncthreads();
    for (int s2 = t; s2 < 2048; s2 += 256) {
        int nl = s2 >> 4, oct = s2 & 15;
        int fg = m0 + oct * 8;
        if (fg < Fp) {
            uint4 v = *(const uint4*)&smem[nl * 128 + ((oct ^ (nl & 7)) << 3)];
            *(uint4*)(out_b + ((size_t)b * NN + n0 + nl) * Fp + fg) = v;
        }
    }
}

// Out[r][g] = relu( sum_p Xp[r][:].Wt[p][g][:] + bias[g] ).
// 256r x 128g tile, 8 waves (512 thr, 4x2 of 64x64 each), gld_lds staging,
// TRIPLE-buffered (depth-2), counted vmcnt(3).
// Ohi/Olo != null: write hi/lo bf16 split (next layer's adj input format).
// Ohi == null (layer3): fused maxpool. 1D grid n_g*4*BC.
__global__ __launch_bounds__(512) void proj_kernel(
    const ushort_t* __restrict__ X0, const ushort_t* __restrict__ X1,
    const ushort_t* __restrict__ X2, const ushort_t* __restrict__ Wt,
    const float* __restrict__ bias, ushort_t* __restrict__ Ohi,
    ushort_t* __restrict__ Olo, float* __restrict__ pool,
    int Fp, int Fo, int b0, int n_g, int bsh) {
    int t = threadIdx.x;
    int L = blockIdx.x;
    int c = L & ((1 << bsh) - 1);
    int rest = L >> bsh;
    int g0 = (rest % n_g) * 128;
    int r0 = (c * 4 + rest / n_g) * 256;
    int lane = t & 63, quad = lane >> 4, l16 = lane & 15, wave = t >> 6;
    int rowoff = (wave >> 1) * 64, coloff = (wave & 1) * 64;

    __shared__ __align__(16) ushort_t smem[36864];   // 3 x (A[256][32] + B[128][32])

    f32x4 acc[4][4];
#pragma unroll
    for (int i = 0; i < 4; ++i)
#pragma unroll
        for (int j = 0; j < 4; ++j) acc[i][j] = (f32x4){0.f, 0.f, 0.f, 0.f};

    int lr = lane >> 2, lk = (lane & 3) * 8;
    int nk = Fp >> 5;
    int NIT = 3 * nk;
    size_t FoFp = (size_t)Fo * Fp;
    size_t r16 = (size_t)16 * Fp;

#define PJ_STAGE(BOFF, CI)                                                    \
    {                                                                         \
        int p_ = (CI) / nk;                                                   \
        int k_ = ((CI) - p_ * nk) * 32 + lk;                                  \
        const ushort_t* Xp_ = (p_ == 0) ? X0 : ((p_ == 1) ? X1 : X2);         \
        const ushort_t* ga_ = Xp_ + (size_t)(r0 + wave * 32 + lr) * Fp + k_;  \
        const ushort_t* gb_ = Wt + (size_t)p_ * FoFp +                        \
                              (size_t)(g0 + wave * 16 + lr) * Fp + k_;        \
        ushort_t* As_ = smem + (BOFF) + wave * 1024;                          \
        ushort_t* Bs_ = smem + (BOFF) + 8192 + wave * 512;                    \
        gld16(ga_, As_);                                                      \
        gld16(ga_ + r16, As_ + 512);                                          \
        gld16(gb_, Bs_);                                                      \
    }
#define PJ_COMP(BOFF)                                                           \
    {                                                                           \
        ushort_t* As_ = smem + (BOFF);                                          \
        ushort_t* Bs_ = As_ + 8192;                                             \
        bf16x8 af[4], bfv[4];                                                   \
        _Pragma("unroll")                                                       \
        for (int i = 0; i < 4; ++i)                                             \
            af[i] = *(const bf16x8*)&As_[(rowoff + i * 16 + l16) * 32 + quad * 8];  \
        _Pragma("unroll")                                                       \
        for (int j = 0; j < 4; ++j)                                             \
            bfv[j] = *(const bf16x8*)&Bs_[(coloff + j * 16 + l16) * 32 + quad * 8]; \
        _Pragma("unroll")                                                       \
        for (int i = 0; i < 4; ++i)                                             \
            _Pragma("unroll")                                                   \
            for (int j = 0; j < 4; ++j)                                         \
                acc[i][j] = __builtin_amdgcn_mfma_f32_16x16x32_bf16(af[i], bfv[j], acc[i][j], 0, 0, 0); \
    }

    PJ_STAGE(0, 0);
    PJ_STAGE(12288, 1);
    int cur = 0;
    for (int ci = 0; ci < NIT; ++ci) {
        if (ci < NIT - 1) { asm volatile("s_waitcnt vmcnt(3)" ::: "memory"); }
        else              { asm volatile("s_waitcnt vmcnt(0)" ::: "memory"); }
        __builtin_amdgcn_s_barrier();
        asm volatile("" ::: "memory");
        if (ci + 2 < NIT) {
            int noff = cur + 24576; if (noff >= 36864) noff -= 36864;
            PJ_STAGE(noff, ci + 2);
        }
        PJ_COMP(cur);
        cur += 12288; if (cur >= 36864) cur = 0;
    }
#undef PJ_STAGE
#undef PJ_COMP

    float bias_l[4];
#pragma unroll
    for (int j = 0; j < 4; ++j) bias_l[j] = bias[g0 + coloff + j * 16 + l16];

    if (Ohi) {
#pragma unroll
        for (int i = 0; i < 4; ++i) {
#pragma unroll
            for (int r = 0; r < 4; ++r) {
                int row = r0 + rowoff + i * 16 + quad * 4 + r;
#pragma unroll
                for (int j = 0; j < 4; ++j) {
                    int g = g0 + coloff + j * 16 + l16;
                    float o = fmaxf(acc[i][j][r] + bias_l[j], 0.f);
                    ushort_t h = f2bf(o);
                    size_t off = (size_t)row * Fo + g;
                    Ohi[off] = h;
                    Olo[off] = f2bf(o - bf2f(h));
                }
            }
        }
    } else {
        float mj[4];
#pragma unroll
        for (int j = 0; j < 4; ++j) {
            float m = 0.f;
#pragma unroll
            for (int i = 0; i < 4; ++i)
#pragma unroll
                for (int r = 0; r < 4; ++r)
                    m = fmaxf(m, acc[i][j][r] + bias_l[j]);
            m = fmaxf(m, 0.f);
            m = fmaxf(m, __shfl_xor(m, 16));
            m = fmaxf(m, __shfl_xor(m, 32));
            mj[j] = m;
        }
        if (quad == 0) {
            int smp = b0 + (r0 >> 10);
#pragma unroll
            for (int j = 0; j < 4; ++j)
                atomicMax((int*)&pool[(size_t)smp * 1024 + g0 + coloff + j * 16 + l16],
                          __float_as_int(mj[j]));
        }
    }
}

// Fused FC chain: 1 block per sample; f1/f2 in LDS.
// out = (relu(relu(pool@W1+b1)@W2+b2))@W3+b3
__global__ __launch_bounds__(256) void fc_fused_kernel(
    const float* __restrict__ In, const float* __restrict__ w1,
    const float* __restrict__ bb1, const float* __restrict__ w2,
    const float* __restrict__ bb2, const float* __restrict__ w3,
    const float* __restrict__ bb3, float* __restrict__ out) {
    int r = blockIdx.x, t = threadIdx.x;
    __shared__ float p[1024];
    __shared__ float f1s[512];
    __shared__ float f2s[128];
#pragma unroll
    for (int k = 0; k < 4; ++k) p[k * 256 + t] = In[(size_t)r * 1024 + k * 256 + t];
    __syncthreads();
#pragma unroll
    for (int cc = 0; cc < 2; ++cc) {
        int c = cc * 256 + t;
        float s = 0.f;
        const float* wp = w1 + c;
#pragma unroll 4
        for (int k = 0; k < 1024; ++k) s += p[k] * wp[(size_t)k * 512];
        f1s[c] = fmaxf(s + bb1[c], 0.f);
    }
    __syncthreads();
    if (t < 128) {
        float s = 0.f;
        const float* wp = w2 + t;
#pragma unroll 4
        for (int k = 0; k < 512; ++k) s += f1s[k] * wp[(size_t)k * 128];
        f2s[t] = fmaxf(s + bb2[t], 0.f);
    }
    __syncthreads();
    if (t < 40) {
        float s = 0.f;
        const float* wp = w3 + t;
#pragma unroll 4
        for (int k = 0; k < 128; ++k) s += f2s[k] * wp[(size_t)k * 40];
        out[(size_t)r * 40 + t] = s + bb3[t];
    }
}

// ---------------------------------------------------------------------------
extern "C" void kernel_launch(void* const* d_in, const int* in_sizes, int n_in,
                              void* d_out, int out_size, void* d_ws, size_t ws_size,
                              hipStream_t stream) {
    const float* x    = (const float*)d_in[0];
    const float* W1   = (const float*)d_in[1];
    const float* b1   = (const float*)d_in[2];
    const float* W2   = (const float*)d_in[3];
    const float* b2   = (const float*)d_in[4];
    const float* W3   = (const float*)d_in[5];
    const float* b3   = (const float*)d_in[6];
    const float* fc1w = (const float*)d_in[7];
    const float* fc1b = (const float*)d_in[8];
    const float* fc2w = (const float*)d_in[9];
    const float* fc2b = (const float*)d_in[10];
    const float* fc3w = (const float*)d_in[11];
    const float* fc3b = (const float*)d_in[12];
    float* out = (float*)d_out;

    // Abf + 5 rotating slots + Wt + sq/degp/dis + pool/f1/f2
    auto need = [](size_t BCv) -> size_t {
        size_t us = (size_t)BCv * 1024;
        return 2 * (us * 1024) + 10 * (us * 512) + 2 * 1781760ull +
               4 * us + 64 * us + 4 * us +
               4 * (32768ull + 16384 + 4096) + 256;
    };
    int BCv = (ws_size >= need(32)) ? 32 : (ws_size >= need(16)) ? 16 : 8;
    int NCH = 32 / BCv;
    int bsh = (BCv == 32) ? 5 : (BCv == 16) ? 4 : 3;

    size_t usc = (size_t)BCv * 1024;
    size_t Asz = usc * 1024;           // ushorts
    size_t SLv = usc * 512;            // ushorts
    ushort_t* Abf = (ushort_t*)d_ws;
    ushort_t* S[5];
    S[0] = Abf + Asz;
    for (int i = 1; i < 5; ++i) S[i] = S[i - 1] + SLv;
    ushort_t* Wt = S[4] + SLv;         // 1781760 ushorts
    float* sq   = (float*)(Wt + 1781760);
    float* degp = sq + usc;            // 16*BC*NN
    float* dis  = degp + 16 * usc;     // BC*NN
    float* pool = dis + usc;           // 32*1024
    float* f1   = pool + 32768;
    float* f2   = f1 + 16384;
    (void)f1; (void)f2;

    init_kernel<<<454, 256, 0, stream>>>(W1, W2, W3, Wt, pool);

    // slot roles per layer: xhi, xlo(=X2b), Xt, X1t, X1b; liveness-verified rotation
    const int MP[3][5] = {{0, 1, 2, 3, 4}, {3, 2, 0, 4, 1}, {4, 0, 3, 1, 2}};

    for (int c = 0; c < NCH; ++c) {
        int b0 = c * BCv;
        struct LayerDef {
            int F, Fp, Fo;
            const ushort_t* Wtl; const float* bias;
        };
        LayerDef L[3] = {
            { 6,   32,  128,  Wt,          b1 },
            { 128, 128, 512,  Wt + 12288,  b2 },
            { 512, 512, 1024, Wt + 208896, b3 },
        };
        for (int li = 0; li < 3; ++li) {
            LayerDef& Ld = L[li];
            int F = Ld.F, Fp = Ld.Fp;
            int ft = (F + 127) / 128;
            int n_g = Ld.Fo / 128;
            ushort_t* xhi = S[MP[li][0]];
            ushort_t* xlo = S[MP[li][1]];
            ushort_t* Xt  = S[MP[li][2]];
            ushort_t* X1t = S[MP[li][3]];
            ushort_t* X1b = S[MP[li][4]];
            prep2_kernel<<<16 * BCv, 256, 0, stream>>>(
                (li == 0) ? (x + (size_t)b0 * NN * 6) : nullptr,
                xhi, xlo, Xt, sq, F, Fp, bsh);
            adj_kernel<<<36 * BCv, 256, 0, stream>>>(xhi, xlo, sq, Abf, degp, Fp, bsh, BCv);
            disscale_kernel<<<16 * BCv, 256, 0, stream>>>(Xt, degp, dis, Fp, bsh, BCv);
            lx_kernel<<<ft * 8 * BCv, 256, 0, stream>>>(
                Abf, dis, Xt, nullptr, X1t, X1b, F, Fp, 0, ft, bsh);
            lx_kernel<<<ft * 8 * BCv, 256, 0, stream>>>(
                Abf, dis, X1t, Xt, nullptr, xlo, F, Fp, 1, ft, bsh);
            // next layer's xhi = this X1t slot, xlo = this Xt slot (both dead here)
            proj_kernel<<<n_g * 4 * BCv, 512, 0, stream>>>(
                xhi, X1b, xlo, Ld.Wtl, Ld.bias,
                (li < 2) ? X1t : nullptr, (li < 2) ? Xt : nullptr,
                pool, Fp, Ld.Fo, b0, n_g, bsh);
        }
    }

    fc_fused_kernel<<<32, 256, 0, stream>>>(pool, fc1w, fc1b, fc2w, fc2b,
                                            fc3w, fc3b, out);
}

// Round 16
// 835.826 us; speedup vs baseline: 1.2570x; 1.2570x over previous
//
#include <hip/hip_runtime.h>
#include <cstddef>

// ---------------------------------------------------------------------------
// ChebNet MFMA bf16: B=32, N=1024, layers 6->128->512->1024 (K=3), maxpool,
// FC 1024->512->128->40. BCv=32 x 1 chunk (~241 MB ws) when ws allows,
// else 16 x 2, else 8 x 4.
// NO fp32 inter-layer activations: proj writes relu(out) directly as hi/lo
// bf16 split; prep2 "lite" mode for layers 2/3. 5 rotating SLv slots.
// init: single kernel = zero(pool) + wconvT x3.
// adj: SYMMETRIC upper-triangle tiles (36/64); reg-staged LDS dbuf; epi v3
//   (both tile layouts via swizzled LDS -> coalesced uint4 stores).
// lx: 128f x 128n tile (2x2 waves, acc[4][4], 16 MFMA/step/wave), gld_lds
//   staging, TRIPLE-buffered, counted vmcnt(4). 48KB LDS -> 3 blocks/CU.
// proj: 256r x 128g tile, 8 waves (512 thr), gld_lds, 3 bufs, vmcnt(3).
// fc: 3 separate kernels (256/128/64-col-tile grids — proven; the fused
//   1-block/sample variant was a 285us parallelism disaster, R15).
// 1D grids, XCD-aware decode (sample = L & (BC-1)).
// ---------------------------------------------------------------------------

#define NN 1024

typedef unsigned short ushort_t;
typedef __bf16 bf16x8 __attribute__((ext_vector_type(8)));
typedef float f32x4 __attribute__((ext_vector_type(4)));

__device__ inline ushort_t f2bf(float f) {
    unsigned int u = __float_as_uint(f);
    u = (u + 0x7fffu + ((u >> 16) & 1u)) >> 16;
    return (ushort_t)u;
}
__device__ inline float bf2f(ushort_t s) {
    return __uint_as_float(((unsigned int)s) << 16);
}

// Async global->LDS, 16B per lane. LDS dest is wave-uniform base; HW writes
// lane l at base + l*16B -> 16 rows x 32 ushorts per instruction,
// lane l -> row (l>>2), col (l&3)*8.
__device__ __attribute__((always_inline)) inline void gld16(
    const ushort_t* g, ushort_t* l) {
    __builtin_amdgcn_global_load_lds(
        (__attribute__((address_space(1))) void*)(ushort_t*)g,
        (__attribute__((address_space(3))) void*)l, 16, 0, 0);
}

// init: blocks [0,16): zero pool; rest: wconvT for W1/W2/W3.
// W[p][Fi][Fo] fp32 -> Wt[p][Fo][Ks] bf16, LDS-tiled transpose, zero-pad K.
__global__ __launch_bounds__(256) void init_kernel(
    const float* __restrict__ W1, const float* __restrict__ W2,
    const float* __restrict__ W3, ushort_t* __restrict__ Wt,
    float* __restrict__ pool) {
    __shared__ float T[64][65];
    int bid = blockIdx.x, t = threadIdx.x;
    if (bid < 16) {
#pragma unroll
        for (int k = 0; k < 8; ++k) pool[bid * 2048 + k * 256 + t] = 0.f;
        return;
    }
    bid -= 16;
    const float* W; ushort_t* wt; int Fi, Fo, Ks, gx, gy, p;
    if (bid < 6)       { W = W1; wt = Wt;          Fi = 6;   Fo = 128;  Ks = 32;
                         gx = bid % 2; gy = 0; p = bid / 2; }
    else if (bid < 54) { int b = bid - 6;  W = W2; wt = Wt + 12288;  Fi = 128; Fo = 512;  Ks = 128;
                         gx = b % 8; gy = (b / 8) % 2; p = b / 16; }
    else               { int b = bid - 54; W = W3; wt = Wt + 208896; Fi = 512; Fo = 1024; Ks = 512;
                         gx = b % 16; gy = (b / 16) % 8; p = b / 128; }
    int k0 = gy * 64, g0 = gx * 64;
#pragma unroll
    for (int q = 0; q < 16; ++q) {
        int kr = (t >> 6) + 4 * q, gc = t & 63;
        int k = k0 + kr, g = g0 + gc;
        T[kr][gc] = (k < Fi && g < Fo) ? W[((size_t)p * Fi + k) * Fo + g] : 0.f;
    }
    __syncthreads();
#pragma unroll
    for (int q = 0; q < 16; ++q) {
        int gr = (t >> 6) + 4 * q, kc = t & 63;
        int g = g0 + gr, k = k0 + kc;
        if (g < Fo && k < Ks)
            wt[((size_t)p * Fo + g) * Ks + k] = f2bf(T[kc][gr]);
    }
}

// Full mode (X != null): read fp32 X, write hi/lo split + Xt + sq.
// Lite mode (X == null): read existing hi/lo (x = hi+lo), write only Xt + sq.
__global__ __launch_bounds__(256) void prep2_kernel(
    const float* __restrict__ X, ushort_t* __restrict__ hi, ushort_t* __restrict__ lo,
    ushort_t* __restrict__ Xt, float* __restrict__ sq, int F, int Fp, int bsh) {
    int L = blockIdx.x;
    int b = L & ((1 << bsh) - 1), n0 = (L >> bsh) * 64;
    int t = threadIdx.x;
    __shared__ float T[64][65];
    __shared__ float red[4][64];
    const float* Xb = X ? (X + ((size_t)b * NN + n0) * F) : nullptr;
    const ushort_t* hb = hi + ((size_t)b * NN + n0) * Fp;
    const ushort_t* lb = lo + ((size_t)b * NN + n0) * Fp;
    float sacc = 0.f;

    for (int f0 = 0; f0 < Fp; f0 += 64) {
        __syncthreads();
#pragma unroll
        for (int p = 0; p < 16; ++p) {
            int nr = (t >> 6) + 4 * p, fc = t & 63;
            int f = f0 + fc;
            float xv = 0.f;
            if (f < F) {
                if (Xb) xv = Xb[(size_t)nr * F + f];
                else {
                    size_t off = (size_t)nr * Fp + f;
                    xv = bf2f(hb[off]) + bf2f(lb[off]);
                }
            }
            T[nr][fc] = xv;
        }
        __syncthreads();
        if (Xb) {
#pragma unroll
            for (int p = 0; p < 16; ++p) {
                int nr = (t >> 6) + 4 * p, fc = t & 63;
                int f = f0 + fc;
                if (f < Fp) {
                    float x = T[nr][fc];
                    ushort_t h = f2bf(x);
                    size_t off = ((size_t)b * NN + n0 + nr) * Fp + f;
                    hi[off] = h;
                    lo[off] = f2bf(x - bf2f(h));
                }
            }
        }
#pragma unroll
        for (int p = 0; p < 16; ++p) {
            int fr = (t >> 6) + 4 * p;
            int f = f0 + fr;
            if (f < F)
                Xt[((size_t)b * Fp + f) * NN + n0 + (t & 63)] = f2bf(T[t & 63][fr]);
        }
        {
            int nl = t & 63, fq = t >> 6;
#pragma unroll
            for (int fc = 0; fc < 16; ++fc) {
                float v = T[nl][fq * 16 + fc];
                sacc += v * v;
            }
        }
    }
    red[t >> 6][t & 63] = sacc;
    __syncthreads();
    if (t < 64)
        sq[(size_t)b * NN + n0 + t] = red[0][t] + red[1][t] + red[2][t] + red[3][t];
}

// A[b,n,m] = exp(2 x_n.x_m - sq_n - sq_m) -> bf16 (split hi/lo MFMA), dbuf;
// reg-staged (proven). SYMMETRIC: upper triangle only (ti<=tj).
// Epilogue v3: exp pass -> two swizzled LDS layouts -> coalesced uint4 stores.
// deg partials: row-sums -> slot tj*2+(wave&1), col-sums -> slot ti*2+(wave>>1).
__global__ __launch_bounds__(256) void adj_kernel(
    const ushort_t* __restrict__ hi, const ushort_t* __restrict__ lo,
    const float* __restrict__ sq, ushort_t* __restrict__ Abf,
    float* __restrict__ deg_part, int Fp, int bsh, int BCv) {
    int t = threadIdx.x;
    int L = blockIdx.x;
    int b = L & ((1 << bsh) - 1);
    int rest = L >> bsh;          // [0,36): triangular tile index
    int ti = 0;
    while (rest >= 8 - ti) { rest -= 8 - ti; ++ti; }
    int tj = ti + rest;
    int n0 = ti * 128, m0 = tj * 128;
    const ushort_t* Hb = hi + (size_t)b * NN * Fp;
    const ushort_t* Lb = lo + (size_t)b * NN * Fp;
    ushort_t* Ab = Abf + (size_t)b * NN * NN;
    const float* sqb = sq + (size_t)b * NN;

    int lane = t & 63, quad = lane >> 4, l16 = lane & 15, wave = t >> 6;
    int rowoff = (wave >> 1) * 64, coloff = (wave & 1) * 64;

    __shared__ __align__(16) ushort_t smem[40960];

    f32x4 acc[4][4];
#pragma unroll
    for (int i = 0; i < 4; ++i)
#pragma unroll
        for (int j = 0; j < 4; ++j) acc[i][j] = (f32x4){0.f, 0.f, 0.f, 0.f};

    int rr0 = t >> 2, kq = (t & 3) * 8;
    int rr1 = rr0 + 64;
    const ushort_t* pAh0 = Hb + (size_t)(n0 + rr0) * Fp + kq;
    const ushort_t* pAh1 = Hb + (size_t)(n0 + rr1) * Fp + kq;
    const ushort_t* pAl0 = Lb + (size_t)(n0 + rr0) * Fp + kq;
    const ushort_t* pAl1 = Lb + (size_t)(n0 + rr1) * Fp + kq;
    const ushort_t* pBh0 = Hb + (size_t)(m0 + rr0) * Fp + kq;
    const ushort_t* pBh1 = Hb + (size_t)(m0 + rr1) * Fp + kq;
    const ushort_t* pBl0 = Lb + (size_t)(m0 + rr0) * Fp + kq;
    const ushort_t* pBl1 = Lb + (size_t)(m0 + rr1) * Fp + kq;
    int o0 = rr0 * 40 + kq, o1 = rr1 * 40 + kq;

    {
        *(uint4*)&smem[o0]         = *(const uint4*)pAh0;
        *(uint4*)&smem[o1]         = *(const uint4*)pAh1;
        *(uint4*)&smem[5120 + o0]  = *(const uint4*)pAl0;
        *(uint4*)&smem[5120 + o1]  = *(const uint4*)pAl1;
        *(uint4*)&smem[10240 + o0] = *(const uint4*)pBh0;
        *(uint4*)&smem[10240 + o1] = *(const uint4*)pBh1;
        *(uint4*)&smem[15360 + o0] = *(const uint4*)pBl0;
        *(uint4*)&smem[15360 + o1] = *(const uint4*)pBl1;
    }
    __syncthreads();

    int NIT = Fp >> 5;
    for (int it = 0; it < NIT; ++it) {
        int cur = (it & 1) * 20480;
        int nxt = 20480 - cur;
        uint4 rh0, rh1, rl0, rl1, sh0, sh1, sl0, sl1;
        if (it + 1 < NIT) {
            int k = (it + 1) * 32;
            rh0 = *(const uint4*)(pAh0 + k); rh1 = *(const uint4*)(pAh1 + k);
            rl0 = *(const uint4*)(pAl0 + k); rl1 = *(const uint4*)(pAl1 + k);
            sh0 = *(const uint4*)(pBh0 + k); sh1 = *(const uint4*)(pBh1 + k);
            sl0 = *(const uint4*)(pBl0 + k); sl1 = *(const uint4*)(pBl1 + k);
        }
        ushort_t* Ah = smem + cur;
        ushort_t* Al = smem + cur + 5120;
        ushort_t* Bh = smem + cur + 10240;
        ushort_t* Bl = smem + cur + 15360;
        bf16x8 ah[4], al[4], bh[4], bl[4];
#pragma unroll
        for (int i = 0; i < 4; ++i) {
            ah[i] = *(const bf16x8*)&Ah[(rowoff + i * 16 + l16) * 40 + quad * 8];
            al[i] = *(const bf16x8*)&Al[(rowoff + i * 16 + l16) * 40 + quad * 8];
        }
#pragma unroll
        for (int j = 0; j < 4; ++j) {
            bh[j] = *(const bf16x8*)&Bh[(coloff + j * 16 + l16) * 40 + quad * 8];
            bl[j] = *(const bf16x8*)&Bl[(coloff + j * 16 + l16) * 40 + quad * 8];
        }
#pragma unroll
        for (int i = 0; i < 4; ++i)
#pragma unroll
            for (int j = 0; j < 4; ++j) {
                acc[i][j] = __builtin_amdgcn_mfma_f32_16x16x32_bf16(al[i], bh[j], acc[i][j], 0, 0, 0);
                acc[i][j] = __builtin_amdgcn_mfma_f32_16x16x32_bf16(ah[i], bl[j], acc[i][j], 0, 0, 0);
                acc[i][j] = __builtin_amdgcn_mfma_f32_16x16x32_bf16(ah[i], bh[j], acc[i][j], 0, 0, 0);
            }
        if (it + 1 < NIT) {
            *(uint4*)&smem[nxt + o0]         = rh0;
            *(uint4*)&smem[nxt + o1]         = rh1;
            *(uint4*)&smem[nxt + 5120 + o0]  = rl0;
            *(uint4*)&smem[nxt + 5120 + o1]  = rl1;
            *(uint4*)&smem[nxt + 10240 + o0] = sh0;
            *(uint4*)&smem[nxt + 10240 + o1] = sh1;
            *(uint4*)&smem[nxt + 15360 + o0] = sl0;
            *(uint4*)&smem[nxt + 15360 + o1] = sl1;
        }
        __syncthreads();
    }

    bool offdiag = (ti != tj);
    float rs[4][4];
    float cs[4] = {0.f, 0.f, 0.f, 0.f};
#pragma unroll
    for (int i = 0; i < 4; ++i)
#pragma unroll
        for (int r = 0; r < 4; ++r) rs[i][r] = 0.f;

    // exp pass: deg sums + BOTH tile layouts into swizzled LDS
#pragma unroll
    for (int j = 0; j < 4; ++j) {
        int ml = coloff + j * 16 + l16;
        float sm = sqb[m0 + ml];
#pragma unroll
        for (int i = 0; i < 4; ++i) {
#pragma unroll
            for (int r = 0; r < 4; ++r) {
                int nl = rowoff + i * 16 + quad * 4 + r;
                float v = __expf(2.f * acc[i][j][r] - sqb[n0 + nl] - sm);
                rs[i][r] += v;
                ushort_t vb = f2bf(v);
                smem[nl * 128 + (((ml >> 3) ^ (nl & 7)) << 3) + (ml & 7)] = vb;
                if (offdiag) {
                    cs[j] += v;
                    smem[16384 + ml * 128 + (((nl >> 3) ^ (ml & 7)) << 3) + (nl & 7)] = vb;
                }
            }
        }
    }
    __syncthreads();
    // direct tile write, coalesced
    for (int s2 = t; s2 < 2048; s2 += 256) {
        int nl = s2 >> 4, oct = s2 & 15;
        uint4 v4 = *(const uint4*)&smem[nl * 128 + ((oct ^ (nl & 7)) << 3)];
        *(uint4*)(Ab + (size_t)(n0 + nl) * NN + m0 + oct * 8) = v4;
    }

    int slot = tj * 2 + (wave & 1);
#pragma unroll
    for (int i = 0; i < 4; ++i)
#pragma unroll
        for (int r = 0; r < 4; ++r) {
            float s = rs[i][r];
            s += __shfl_xor(s, 1);
            s += __shfl_xor(s, 2);
            s += __shfl_xor(s, 4);
            s += __shfl_xor(s, 8);
            if (l16 == 0)
                deg_part[((size_t)slot * BCv + b) * NN + n0 + rowoff + i * 16 + quad * 4 + r] = s;
        }

    if (offdiag) {
        // column sums -> mirror rows' partials: slot ti*2 + (wave>>1)
#pragma unroll
        for (int j = 0; j < 4; ++j) {
            float s = cs[j];
            s += __shfl_xor(s, 16);
            s += __shfl_xor(s, 32);
            cs[j] = s;
        }
        if (quad == 0) {
#pragma unroll
            for (int j = 0; j < 4; ++j)
                deg_part[((size_t)(ti * 2 + (wave >> 1)) * BCv + b) * NN +
                         m0 + coloff + j * 16 + l16] = cs[j];
        }
        // mirrored tile write, coalesced (layout 2 written pre-sync above)
        for (int s2 = t; s2 < 2048; s2 += 256) {
            int ml = s2 >> 4, oct = s2 & 15;
            uint4 v4 = *(const uint4*)&smem[16384 + ml * 128 + ((oct ^ (ml & 7)) << 3)];
            *(uint4*)(Ab + (size_t)(m0 + ml) * NN + n0 + oct * 8) = v4;
        }
    }
}

// dis[b][n] = rsqrt(sum of 16 deg partials); Xt[b][f][n0..] *= dis[n] in place.
__global__ __launch_bounds__(256) void disscale_kernel(
    ushort_t* __restrict__ Xt, const float* __restrict__ deg_part,
    float* __restrict__ dis, int Fp, int bsh, int BCv) {
    int L = blockIdx.x;
    int b = L & ((1 << bsh) - 1), n0 = (L >> bsh) * 64;
    int t = threadIdx.x;
    __shared__ float dloc[64];
    if (t < 64) {
        float s = 0.f;
#pragma unroll
        for (int k = 0; k < 16; ++k) s += deg_part[((size_t)k * BCv + b) * NN + n0 + t];
        float d = rsqrtf(s);
        dloc[t] = d;
        dis[(size_t)b * NN + n0 + t] = d;
    }
    __syncthreads();
    int lane = t & 63, fq = t >> 6;
    float d = dloc[lane];
    ushort_t* Xb = Xt + (size_t)b * Fp * NN + n0 + lane;
    for (int f = fq; f < Fp; f += 4) {
        size_t off = (size_t)f * NN;
        Xb[off] = f2bf(bf2f(Xb[off]) * d);
    }
}

// lx: acc[f][n] = sum_k in_t[f][k] * A[n][k]  (A raw symmetric).
// Tile 128f x 128n, 4 waves (2x2: rowoff=(w>>1)*64, coloff=(w&1)*64),
// acc[4][4], K=1024 in 32 steps. gld_lds staging, TRIPLE-buffered (depth-2),
// raw s_barrier + counted vmcnt(4). 48KB LDS -> 3 blocks/CU.
// mode0: out_t = xin - dn^2*acc; out_b = inv*xin - dn*acc.
// mode1: out_b = inv*(2*xin - x0) - 2*dn*acc.
__global__ __launch_bounds__(256) void lx_kernel(
    const ushort_t* __restrict__ Abf, const float* __restrict__ dis,
    const ushort_t* __restrict__ in_t, const ushort_t* __restrict__ x0t,
    ushort_t* __restrict__ out_t, ushort_t* __restrict__ out_b,
    int F, int Fp, int mode, int ft, int bsh) {
    int t = threadIdx.x;
    int L = blockIdx.x;
    int b = L & ((1 << bsh) - 1);
    int rest = L >> bsh;
    int m0 = (rest % ft) * 128;   // f tile (128)
    int n0 = (rest / ft) * 128;   // n tile (128)
    const ushort_t* Ain = in_t + (size_t)b * Fp * NN;
    const ushort_t* Ab = Abf + (size_t)b * NN * NN;

    int lane = t & 63, quad = lane >> 4, l16 = lane & 15, wave = t >> 6;
    int rowoff = (wave >> 1) * 64, coloff = (wave & 1) * 64;

    __shared__ __align__(16) ushort_t smem[24576];   // 3 x (A[128][32] + B[128][32])

    f32x4 acc[4][4];
#pragma unroll
    for (int i = 0; i < 4; ++i)
#pragma unroll
        for (int j = 0; j < 4; ++j) acc[i][j] = (f32x4){0.f, 0.f, 0.f, 0.f};

    int lr = lane >> 2, lk = (lane & 3) * 8;
    const ushort_t* gA = Ain + (size_t)(m0 + wave * 32 + lr) * NN + lk;
    const ushort_t* gB = Ab + (size_t)(n0 + wave * 32 + lr) * NN + lk;

#define LX_STAGE(BOFF, CI)                                            \
    {                                                                 \
        int k_ = (CI) * 32;                                           \
        ushort_t* As_ = smem + (BOFF) + wave * 1024;                  \
        ushort_t* Bs_ = smem + (BOFF) + 4096 + wave * 1024;           \
        gld16(gA + k_, As_);                                          \
        gld16(gA + (size_t)16 * NN + k_, As_ + 512);                  \
        gld16(gB + k_, Bs_);                                          \
        gld16(gB + (size_t)16 * NN + k_, Bs_ + 512);                  \
    }
#define LX_COMP(BOFF)                                                            \
    {                                                                            \
        ushort_t* As_ = smem + (BOFF);                                           \
        ushort_t* Bs_ = As_ + 4096;                                              \
        bf16x8 af[4], bfv[4];                                                    \
        _Pragma("unroll")                                                        \
        for (int i = 0; i < 4; ++i)                                              \
            af[i] = *(const bf16x8*)&As_[(rowoff + i * 16 + l16) * 32 + quad * 8]; \
        _Pragma("unroll")                                                        \
        for (int j = 0; j < 4; ++j)                                              \
            bfv[j] = *(const bf16x8*)&Bs_[(coloff + j * 16 + l16) * 32 + quad * 8]; \
        _Pragma("unroll")                                                        \
        for (int i = 0; i < 4; ++i)                                              \
            _Pragma("unroll")                                                    \
            for (int j = 0; j < 4; ++j)                                          \
                acc[i][j] = __builtin_amdgcn_mfma_f32_16x16x32_bf16(af[i], bfv[j], acc[i][j], 0, 0, 0); \
    }

    LX_STAGE(0, 0);
    LX_STAGE(8192, 1);
    int cur = 0;
    for (int ci = 0; ci < 32; ++ci) {
        if (ci < 31) { asm volatile("s_waitcnt vmcnt(4)" ::: "memory"); }
        else         { asm volatile("s_waitcnt vmcnt(0)" ::: "memory"); }
        __builtin_amdgcn_s_barrier();
        asm volatile("" ::: "memory");
        if (ci + 2 < 32) {
            int noff = cur + 16384; if (noff >= 24576) noff -= 24576;
            LX_STAGE(noff, ci + 2);
        }
        LX_COMP(cur);
        cur += 8192; if (cur >= 24576) cur = 0;
    }
#undef LX_STAGE
#undef LX_COMP
    __syncthreads();   // all waves done reading stage bufs before epilogue reuse

#pragma unroll
    for (int j = 0; j < 4; ++j) {
        int nl = coloff + j * 16 + l16;
        int n = n0 + nl;
        float dn = dis[(size_t)b * NN + n];
        float inv = 1.f / dn;
        float dn2 = dn * dn;
#pragma unroll
        for (int i = 0; i < 4; ++i) {
#pragma unroll
            for (int r = 0; r < 4; ++r) {
                int fl = rowoff + i * 16 + quad * 4 + r;
                int f = m0 + fl;
                float o = 0.f;
                if (f < F) {
                    float a = acc[i][j][r];
                    size_t off = (size_t)f * NN + n;
                    float xin = bf2f(Ain[off]);
                    if (mode == 0) {
                        out_t[(size_t)b * Fp * NN + off] = f2bf(xin - dn2 * a);
                        o = inv * xin - dn * a;
                    } else {
                        float x0 = bf2f(x0t[(size_t)b * Fp * NN + off]);
                        o = inv * (2.f * xin - x0) - 2.f * dn * a;
                    }
                }
                smem[nl * 128 + (((fl >> 3) ^ (nl & 7)) << 3) + (fl & 7)] = f2bf(o);
            }
        }
    }
    __syncthreads();
    for (int s2 = t; s2 < 2048; s2 += 256) {
        int nl = s2 >> 4, oct = s2 & 15;
        int fg = m0 + oct * 8;
        if (fg < Fp) {
            uint4 v = *(const uint4*)&smem[nl * 128 + ((oct ^ (nl & 7)) << 3)];
            *(uint4*)(out_b + ((size_t)b * NN + n0 + nl) * Fp + fg) = v;
        }
    }
}

// Out[r][g] = relu( sum_p Xp[r][:].Wt[p][g][:] + bias[g] ).
// 256r x 128g tile, 8 waves (512 thr, 4x2 of 64x64 each), gld_lds staging,
// TRIPLE-buffered (depth-2), counted vmcnt(3).
// Ohi/Olo != null: write hi/lo bf16 split (next layer's adj input format).
// Ohi == null (layer3): fused maxpool. 1D grid n_g*4*BC.
__global__ __launch_bounds__(512) void proj_kernel(
    const ushort_t* __restrict__ X0, const ushort_t* __restrict__ X1,
    const ushort_t* __restrict__ X2, const ushort_t* __restrict__ Wt,
    const float* __restrict__ bias, ushort_t* __restrict__ Ohi,
    ushort_t* __restrict__ Olo, float* __restrict__ pool,
    int Fp, int Fo, int b0, int n_g, int bsh) {
    int t = threadIdx.x;
    int L = blockIdx.x;
    int c = L & ((1 << bsh) - 1);
    int rest = L >> bsh;
    int g0 = (rest % n_g) * 128;
    int r0 = (c * 4 + rest / n_g) * 256;
    int lane = t & 63, quad = lane >> 4, l16 = lane & 15, wave = t >> 6;
    int rowoff = (wave >> 1) * 64, coloff = (wave & 1) * 64;

    __shared__ __align__(16) ushort_t smem[36864];   // 3 x (A[256][32] + B[128][32])

    f32x4 acc[4][4];
#pragma unroll
    for (int i = 0; i < 4; ++i)
#pragma unroll
        for (int j = 0; j < 4; ++j) acc[i][j] = (f32x4){0.f, 0.f, 0.f, 0.f};

    int lr = lane >> 2, lk = (lane & 3) * 8;
    int nk = Fp >> 5;
    int NIT = 3 * nk;
    size_t FoFp = (size_t)Fo * Fp;
    size_t r16 = (size_t)16 * Fp;

#define PJ_STAGE(BOFF, CI)                                                    \
    {                                                                         \
        int p_ = (CI) / nk;                                                   \
        int k_ = ((CI) - p_ * nk) * 32 + lk;                                  \
        const ushort_t* Xp_ = (p_ == 0) ? X0 : ((p_ == 1) ? X1 : X2);         \
        const ushort_t* ga_ = Xp_ + (size_t)(r0 + wave * 32 + lr) * Fp + k_;  \
        const ushort_t* gb_ = Wt + (size_t)p_ * FoFp +                        \
                              (size_t)(g0 + wave * 16 + lr) * Fp + k_;        \
        ushort_t* As_ = smem + (BOFF) + wave * 1024;                          \
        ushort_t* Bs_ = smem + (BOFF) + 8192 + wave * 512;                    \
        gld16(ga_, As_);                                                      \
        gld16(ga_ + r16, As_ + 512);                                          \
        gld16(gb_, Bs_);                                                      \
    }
#define PJ_COMP(BOFF)                                                           \
    {                                                                           \
        ushort_t* As_ = smem + (BOFF);                                          \
        ushort_t* Bs_ = As_ + 8192;                                             \
        bf16x8 af[4], bfv[4];                                                   \
        _Pragma("unroll")                                                       \
        for (int i = 0; i < 4; ++i)                                             \
            af[i] = *(const bf16x8*)&As_[(rowoff + i * 16 + l16) * 32 + quad * 8];  \
        _Pragma("unroll")                                                       \
        for (int j = 0; j < 4; ++j)                                             \
            bfv[j] = *(const bf16x8*)&Bs_[(coloff + j * 16 + l16) * 32 + quad * 8]; \
        _Pragma("unroll")                                                       \
        for (int i = 0; i < 4; ++i)                                             \
            _Pragma("unroll")                                                   \
            for (int j = 0; j < 4; ++j)                                         \
                acc[i][j] = __builtin_amdgcn_mfma_f32_16x16x32_bf16(af[i], bfv[j], acc[i][j], 0, 0, 0); \
    }

    PJ_STAGE(0, 0);
    PJ_STAGE(12288, 1);
    int cur = 0;
    for (int ci = 0; ci < NIT; ++ci) {
        if (ci < NIT - 1) { asm volatile("s_waitcnt vmcnt(3)" ::: "memory"); }
        else              { asm volatile("s_waitcnt vmcnt(0)" ::: "memory"); }
        __builtin_amdgcn_s_barrier();
        asm volatile("" ::: "memory");
        if (ci + 2 < NIT) {
            int noff = cur + 24576; if (noff >= 36864) noff -= 36864;
            PJ_STAGE(noff, ci + 2);
        }
        PJ_COMP(cur);
        cur += 12288; if (cur >= 36864) cur = 0;
    }
#undef PJ_STAGE
#undef PJ_COMP

    float bias_l[4];
#pragma unroll
    for (int j = 0; j < 4; ++j) bias_l[j] = bias[g0 + coloff + j * 16 + l16];

    if (Ohi) {
#pragma unroll
        for (int i = 0; i < 4; ++i) {
#pragma unroll
            for (int r = 0; r < 4; ++r) {
                int row = r0 + rowoff + i * 16 + quad * 4 + r;
#pragma unroll
                for (int j = 0; j < 4; ++j) {
                    int g = g0 + coloff + j * 16 + l16;
                    float o = fmaxf(acc[i][j][r] + bias_l[j], 0.f);
                    ushort_t h = f2bf(o);
                    size_t off = (size_t)row * Fo + g;
                    Ohi[off] = h;
                    Olo[off] = f2bf(o - bf2f(h));
                }
            }
        }
    } else {
        float mj[4];
#pragma unroll
        for (int j = 0; j < 4; ++j) {
            float m = 0.f;
#pragma unroll
            for (int i = 0; i < 4; ++i)
#pragma unroll
                for (int r = 0; r < 4; ++r)
                    m = fmaxf(m, acc[i][j][r] + bias_l[j]);
            m = fmaxf(m, 0.f);
            m = fmaxf(m, __shfl_xor(m, 16));
            m = fmaxf(m, __shfl_xor(m, 32));
            mj[j] = m;
        }
        if (quad == 0) {
            int smp = b0 + (r0 >> 10);
#pragma unroll
            for (int j = 0; j < 4; ++j)
                atomicMax((int*)&pool[(size_t)smp * 1024 + g0 + coloff + j * 16 + l16],
                          __float_as_int(mj[j]));
        }
    }
}

// fc: block = (row, 64-col tile); 4 K-slices x 64 cols; LDS reduce.
__global__ __launch_bounds__(256) void fc_kernel(
    const float* __restrict__ In, const float* __restrict__ W,
    const float* __restrict__ bias, float* __restrict__ out,
    int K, int Nout, int relu) {
    int r = blockIdx.y;
    int c0 = blockIdx.x * 64;
    int t = threadIdx.x;
    int cl = t & 63, ks = t >> 6;
    int c = c0 + cl;
    int kchunk = K >> 2;
    int k0 = ks * kchunk, k1 = k0 + kchunk;
    float s = 0.f;
    if (c < Nout) {
        const float* ip = In + (size_t)r * K;
        const float* wp = W + c;
#pragma unroll 4
        for (int k = k0; k < k1; ++k) s += ip[k] * wp[(size_t)k * Nout];
    }
    __shared__ float red[4][64];
    red[ks][cl] = s;
    __syncthreads();
    if (t < 64 && c0 + t < Nout) {
        float v = red[0][t] + red[1][t] + red[2][t] + red[3][t] + bias[c0 + t];
        if (relu) v = fmaxf(v, 0.f);
        out[(size_t)r * Nout + c0 + t] = v;
    }
}

// ---------------------------------------------------------------------------
extern "C" void kernel_launch(void* const* d_in, const int* in_sizes, int n_in,
                              void* d_out, int out_size, void* d_ws, size_t ws_size,
                              hipStream_t stream) {
    const float* x    = (const float*)d_in[0];
    const float* W1   = (const float*)d_in[1];
    const float* b1   = (const float*)d_in[2];
    const float* W2   = (const float*)d_in[3];
    const float* b2   = (const float*)d_in[4];
    const float* W3   = (const float*)d_in[5];
    const float* b3   = (const float*)d_in[6];
    const float* fc1w = (const float*)d_in[7];
    const float* fc1b = (const float*)d_in[8];
    const float* fc2w = (const float*)d_in[9];
    const float* fc2b = (const float*)d_in[10];
    const float* fc3w = (const float*)d_in[11];
    const float* fc3b = (const float*)d_in[12];
    float* out = (float*)d_out;

    // Abf + 5 rotating slots + Wt + sq/degp/dis + pool/f1/f2
    auto need = [](size_t BCv) -> size_t {
        size_t us = (size_t)BCv * 1024;
        return 2 * (us * 1024) + 10 * (us * 512) + 2 * 1781760ull +
               4 * us + 64 * us + 4 * us +
               4 * (32768ull + 16384 + 4096) + 256;
    };
    int BCv = (ws_size >= need(32)) ? 32 : (ws_size >= need(16)) ? 16 : 8;
    int NCH = 32 / BCv;
    int bsh = (BCv == 32) ? 5 : (BCv == 16) ? 4 : 3;

    size_t usc = (size_t)BCv * 1024;
    size_t Asz = usc * 1024;           // ushorts
    size_t SLv = usc * 512;            // ushorts
    ushort_t* Abf = (ushort_t*)d_ws;
    ushort_t* S[5];
    S[0] = Abf + Asz;
    for (int i = 1; i < 5; ++i) S[i] = S[i - 1] + SLv;
    ushort_t* Wt = S[4] + SLv;         // 1781760 ushorts
    float* sq   = (float*)(Wt + 1781760);
    float* degp = sq + usc;            // 16*BC*NN
    float* dis  = degp + 16 * usc;     // BC*NN
    float* pool = dis + usc;           // 32*1024
    float* f1   = pool + 32768;
    float* f2   = f1 + 16384;

    init_kernel<<<454, 256, 0, stream>>>(W1, W2, W3, Wt, pool);

    // slot roles per layer: xhi, xlo(=X2b), Xt, X1t, X1b; liveness-verified rotation
    const int MP[3][5] = {{0, 1, 2, 3, 4}, {3, 2, 0, 4, 1}, {4, 0, 3, 1, 2}};

    for (int c = 0; c < NCH; ++c) {
        int b0 = c * BCv;
        struct LayerDef {
            int F, Fp, Fo;
            const ushort_t* Wtl; const float* bias;
        };
        LayerDef L[3] = {
            { 6,   32,  128,  Wt,          b1 },
            { 128, 128, 512,  Wt + 12288,  b2 },
            { 512, 512, 1024, Wt + 208896, b3 },
        };
        for (int li = 0; li < 3; ++li) {
            LayerDef& Ld = L[li];
            int F = Ld.F, Fp = Ld.Fp;
            int ft = (F + 127) / 128;
            int n_g = Ld.Fo / 128;
            ushort_t* xhi = S[MP[li][0]];
            ushort_t* xlo = S[MP[li][1]];
            ushort_t* Xt  = S[MP[li][2]];
            ushort_t* X1t = S[MP[li][3]];
            ushort_t* X1b = S[MP[li][4]];
            prep2_kernel<<<16 * BCv, 256, 0, stream>>>(
                (li == 0) ? (x + (size_t)b0 * NN * 6) : nullptr,
                xhi, xlo, Xt, sq, F, Fp, bsh);
            adj_kernel<<<36 * BCv, 256, 0, stream>>>(xhi, xlo, sq, Abf, degp, Fp, bsh, BCv);
            disscale_kernel<<<16 * BCv, 256, 0, stream>>>(Xt, degp, dis, Fp, bsh, BCv);
            lx_kernel<<<ft * 8 * BCv, 256, 0, stream>>>(
                Abf, dis, Xt, nullptr, X1t, X1b, F, Fp, 0, ft, bsh);
            lx_kernel<<<ft * 8 * BCv, 256, 0, stream>>>(
                Abf, dis, X1t, Xt, nullptr, xlo, F, Fp, 1, ft, bsh);
            // next layer's xhi = this X1t slot, xlo = this Xt slot (both dead here)
            proj_kernel<<<n_g * 4 * BCv, 512, 0, stream>>>(
                xhi, X1b, xlo, Ld.Wtl, Ld.bias,
                (li < 2) ? X1t : nullptr, (li < 2) ? Xt : nullptr,
                pool, Fp, Ld.Fo, b0, n_g, bsh);
        }
    }

    fc_kernel<<<dim3(8, 32), 256, 0, stream>>>(pool, fc1w, fc1b, f1, 1024, 512, 1);
    fc_kernel<<<dim3(2, 32), 256, 0, stream>>>(f1, fc2w, fc2b, f2, 512, 128, 1);
    fc_kernel<<<dim3(1, 32), 256, 0, stream>>>(f2, fc3w, fc3b, out, 128, 40, 0);
}

// Round 17
// 797.309 us; speedup vs baseline: 1.3177x; 1.0483x over previous
//
#include <hip/hip_runtime.h>
#include <cstddef>

// ---------------------------------------------------------------------------
// ChebNet MFMA bf16: B=32, N=1024, layers 6->128->512->1024 (K=3), maxpool,
// FC 1024->512->128->40. BCv=32 x 1 chunk (~241 MB ws) when ws allows,
// else 16 x 2, else 8 x 4.
// NO fp32 inter-layer activations: proj writes relu(out) directly as hi/lo
// bf16 split; prep2 "lite" mode for layers 2/3. 5 rotating SLv slots.
// init: single kernel = zero(pool) + wconvT x3.
// adj: SYMMETRIC upper-triangle tiles (36/64); reg-staged LDS dbuf; epi v3
//   (both tile layouts via swizzled LDS -> coalesced uint4 stores).
// lx: 128f x 64n tile (PROVEN; 128x128 regressed: 48KB LDS -> 3 blocks/CU
//   + ragged grid tail, R16), gld_lds, TRIPLE-buffered, counted vmcnt(3).
// proj: 256r x 128g tile, 8 waves (512 thr), gld_lds, 3 bufs, vmcnt(3).
// fc: 3 separate kernels (proven; fused 1-block/sample was 285us, R15).
// 1D grids, XCD-aware decode (sample = L & (BC-1)).
// ---------------------------------------------------------------------------

#define NN 1024

typedef unsigned short ushort_t;
typedef __bf16 bf16x8 __attribute__((ext_vector_type(8)));
typedef float f32x4 __attribute__((ext_vector_type(4)));

__device__ inline ushort_t f2bf(float f) {
    unsigned int u = __float_as_uint(f);
    u = (u + 0x7fffu + ((u >> 16) & 1u)) >> 16;
    return (ushort_t)u;
}
__device__ inline float bf2f(ushort_t s) {
    return __uint_as_float(((unsigned int)s) << 16);
}

// Async global->LDS, 16B per lane. LDS dest is wave-uniform base; HW writes
// lane l at base + l*16B -> 16 rows x 32 ushorts per instruction,
// lane l -> row (l>>2), col (l&3)*8.
__device__ __attribute__((always_inline)) inline void gld16(
    const ushort_t* g, ushort_t* l) {
    __builtin_amdgcn_global_load_lds(
        (__attribute__((address_space(1))) void*)(ushort_t*)g,
        (__attribute__((address_space(3))) void*)l, 16, 0, 0);
}

// init: blocks [0,16): zero pool; rest: wconvT for W1/W2/W3.
// W[p][Fi][Fo] fp32 -> Wt[p][Fo][Ks] bf16, LDS-tiled transpose, zero-pad K.
__global__ __launch_bounds__(256) void init_kernel(
    const float* __restrict__ W1, const float* __restrict__ W2,
    const float* __restrict__ W3, ushort_t* __restrict__ Wt,
    float* __restrict__ pool) {
    __shared__ float T[64][65];
    int bid = blockIdx.x, t = threadIdx.x;
    if (bid < 16) {
#pragma unroll
        for (int k = 0; k < 8; ++k) pool[bid * 2048 + k * 256 + t] = 0.f;
        return;
    }
    bid -= 16;
    const float* W; ushort_t* wt; int Fi, Fo, Ks, gx, gy, p;
    if (bid < 6)       { W = W1; wt = Wt;          Fi = 6;   Fo = 128;  Ks = 32;
                         gx = bid % 2; gy = 0; p = bid / 2; }
    else if (bid < 54) { int b = bid - 6;  W = W2; wt = Wt + 12288;  Fi = 128; Fo = 512;  Ks = 128;
                         gx = b % 8; gy = (b / 8) % 2; p = b / 16; }
    else               { int b = bid - 54; W = W3; wt = Wt + 208896; Fi = 512; Fo = 1024; Ks = 512;
                         gx = b % 16; gy = (b / 16) % 8; p = b / 128; }
    int k0 = gy * 64, g0 = gx * 64;
#pragma unroll
    for (int q = 0; q < 16; ++q) {
        int kr = (t >> 6) + 4 * q, gc = t & 63;
        int k = k0 + kr, g = g0 + gc;
        T[kr][gc] = (k < Fi && g < Fo) ? W[((size_t)p * Fi + k) * Fo + g] : 0.f;
    }
    __syncthreads();
#pragma unroll
    for (int q = 0; q < 16; ++q) {
        int gr = (t >> 6) + 4 * q, kc = t & 63;
        int g = g0 + gr, k = k0 + kc;
        if (g < Fo && k < Ks)
            wt[((size_t)p * Fo + g) * Ks + k] = f2bf(T[kc][gr]);
    }
}

// Full mode (X != null): read fp32 X, write hi/lo split + Xt + sq.
// Lite mode (X == null): read existing hi/lo (x = hi+lo), write only Xt + sq.
__global__ __launch_bounds__(256) void prep2_kernel(
    const float* __restrict__ X, ushort_t* __restrict__ hi, ushort_t* __restrict__ lo,
    ushort_t* __restrict__ Xt, float* __restrict__ sq, int F, int Fp, int bsh) {
    int L = blockIdx.x;
    int b = L & ((1 << bsh) - 1), n0 = (L >> bsh) * 64;
    int t = threadIdx.x;
    __shared__ float T[64][65];
    __shared__ float red[4][64];
    const float* Xb = X ? (X + ((size_t)b * NN + n0) * F) : nullptr;
    const ushort_t* hb = hi + ((size_t)b * NN + n0) * Fp;
    const ushort_t* lb = lo + ((size_t)b * NN + n0) * Fp;
    float sacc = 0.f;

    for (int f0 = 0; f0 < Fp; f0 += 64) {
        __syncthreads();
#pragma unroll
        for (int p = 0; p < 16; ++p) {
            int nr = (t >> 6) + 4 * p, fc = t & 63;
            int f = f0 + fc;
            float xv = 0.f;
            if (f < F) {
                if (Xb) xv = Xb[(size_t)nr * F + f];
                else {
                    size_t off = (size_t)nr * Fp + f;
                    xv = bf2f(hb[off]) + bf2f(lb[off]);
                }
            }
            T[nr][fc] = xv;
        }
        __syncthreads();
        if (Xb) {
#pragma unroll
            for (int p = 0; p < 16; ++p) {
                int nr = (t >> 6) + 4 * p, fc = t & 63;
                int f = f0 + fc;
                if (f < Fp) {
                    float x = T[nr][fc];
                    ushort_t h = f2bf(x);
                    size_t off = ((size_t)b * NN + n0 + nr) * Fp + f;
                    hi[off] = h;
                    lo[off] = f2bf(x - bf2f(h));
                }
            }
        }
#pragma unroll
        for (int p = 0; p < 16; ++p) {
            int fr = (t >> 6) + 4 * p;
            int f = f0 + fr;
            if (f < F)
                Xt[((size_t)b * Fp + f) * NN + n0 + (t & 63)] = f2bf(T[t & 63][fr]);
        }
        {
            int nl = t & 63, fq = t >> 6;
#pragma unroll
            for (int fc = 0; fc < 16; ++fc) {
                float v = T[nl][fq * 16 + fc];
                sacc += v * v;
            }
        }
    }
    red[t >> 6][t & 63] = sacc;
    __syncthreads();
    if (t < 64)
        sq[(size_t)b * NN + n0 + t] = red[0][t] + red[1][t] + red[2][t] + red[3][t];
}

// A[b,n,m] = exp(2 x_n.x_m - sq_n - sq_m) -> bf16 (split hi/lo MFMA), dbuf;
// reg-staged (proven). SYMMETRIC: upper triangle only (ti<=tj).
// Epilogue v3: exp pass -> two swizzled LDS layouts -> coalesced uint4 stores.
// deg partials: row-sums -> slot tj*2+(wave&1), col-sums -> slot ti*2+(wave>>1).
__global__ __launch_bounds__(256) void adj_kernel(
    const ushort_t* __restrict__ hi, const ushort_t* __restrict__ lo,
    const float* __restrict__ sq, ushort_t* __restrict__ Abf,
    float* __restrict__ deg_part, int Fp, int bsh, int BCv) {
    int t = threadIdx.x;
    int L = blockIdx.x;
    int b = L & ((1 << bsh) - 1);
    int rest = L >> bsh;          // [0,36): triangular tile index
    int ti = 0;
    while (rest >= 8 - ti) { rest -= 8 - ti; ++ti; }
    int tj = ti + rest;
    int n0 = ti * 128, m0 = tj * 128;
    const ushort_t* Hb = hi + (size_t)b * NN * Fp;
    const ushort_t* Lb = lo + (size_t)b * NN * Fp;
    ushort_t* Ab = Abf + (size_t)b * NN * NN;
    const float* sqb = sq + (size_t)b * NN;

    int lane = t & 63, quad = lane >> 4, l16 = lane & 15, wave = t >> 6;
    int rowoff = (wave >> 1) * 64, coloff = (wave & 1) * 64;

    __shared__ __align__(16) ushort_t smem[40960];

    f32x4 acc[4][4];
#pragma unroll
    for (int i = 0; i < 4; ++i)
#pragma unroll
        for (int j = 0; j < 4; ++j) acc[i][j] = (f32x4){0.f, 0.f, 0.f, 0.f};

    int rr0 = t >> 2, kq = (t & 3) * 8;
    int rr1 = rr0 + 64;
    const ushort_t* pAh0 = Hb + (size_t)(n0 + rr0) * Fp + kq;
    const ushort_t* pAh1 = Hb + (size_t)(n0 + rr1) * Fp + kq;
    const ushort_t* pAl0 = Lb + (size_t)(n0 + rr0) * Fp + kq;
    const ushort_t* pAl1 = Lb + (size_t)(n0 + rr1) * Fp + kq;
    const ushort_t* pBh0 = Hb + (size_t)(m0 + rr0) * Fp + kq;
    const ushort_t* pBh1 = Hb + (size_t)(m0 + rr1) * Fp + kq;
    const ushort_t* pBl0 = Lb + (size_t)(m0 + rr0) * Fp + kq;
    const ushort_t* pBl1 = Lb + (size_t)(m0 + rr1) * Fp + kq;
    int o0 = rr0 * 40 + kq, o1 = rr1 * 40 + kq;

    {
        *(uint4*)&smem[o0]         = *(const uint4*)pAh0;
        *(uint4*)&smem[o1]         = *(const uint4*)pAh1;
        *(uint4*)&smem[5120 + o0]  = *(const uint4*)pAl0;
        *(uint4*)&smem[5120 + o1]  = *(const uint4*)pAl1;
        *(uint4*)&smem[10240 + o0] = *(const uint4*)pBh0;
        *(uint4*)&smem[10240 + o1] = *(const uint4*)pBh1;
        *(uint4*)&smem[15360 + o0] = *(const uint4*)pBl0;
        *(uint4*)&smem[15360 + o1] = *(const uint4*)pBl1;
    }
    __syncthreads();

    int NIT = Fp >> 5;
    for (int it = 0; it < NIT; ++it) {
        int cur = (it & 1) * 20480;
        int nxt = 20480 - cur;
        uint4 rh0, rh1, rl0, rl1, sh0, sh1, sl0, sl1;
        if (it + 1 < NIT) {
            int k = (it + 1) * 32;
            rh0 = *(const uint4*)(pAh0 + k); rh1 = *(const uint4*)(pAh1 + k);
            rl0 = *(const uint4*)(pAl0 + k); rl1 = *(const uint4*)(pAl1 + k);
            sh0 = *(const uint4*)(pBh0 + k); sh1 = *(const uint4*)(pBh1 + k);
            sl0 = *(const uint4*)(pBl0 + k); sl1 = *(const uint4*)(pBl1 + k);
        }
        ushort_t* Ah = smem + cur;
        ushort_t* Al = smem + cur + 5120;
        ushort_t* Bh = smem + cur + 10240;
        ushort_t* Bl = smem + cur + 15360;
        bf16x8 ah[4], al[4], bh[4], bl[4];
#pragma unroll
        for (int i = 0; i < 4; ++i) {
            ah[i] = *(const bf16x8*)&Ah[(rowoff + i * 16 + l16) * 40 + quad * 8];
            al[i] = *(const bf16x8*)&Al[(rowoff + i * 16 + l16) * 40 + quad * 8];
        }
#pragma unroll
        for (int j = 0; j < 4; ++j) {
            bh[j] = *(const bf16x8*)&Bh[(coloff + j * 16 + l16) * 40 + quad * 8];
            bl[j] = *(const bf16x8*)&Bl[(coloff + j * 16 + l16) * 40 + quad * 8];
        }
#pragma unroll
        for (int i = 0; i < 4; ++i)
#pragma unroll
            for (int j = 0; j < 4; ++j) {
                acc[i][j] = __builtin_amdgcn_mfma_f32_16x16x32_bf16(al[i], bh[j], acc[i][j], 0, 0, 0);
                acc[i][j] = __builtin_amdgcn_mfma_f32_16x16x32_bf16(ah[i], bl[j], acc[i][j], 0, 0, 0);
                acc[i][j] = __builtin_amdgcn_mfma_f32_16x16x32_bf16(ah[i], bh[j], acc[i][j], 0, 0, 0);
            }
        if (it + 1 < NIT) {
            *(uint4*)&smem[nxt + o0]         = rh0;
            *(uint4*)&smem[nxt + o1]         = rh1;
            *(uint4*)&smem[nxt + 5120 + o0]  = rl0;
            *(uint4*)&smem[nxt + 5120 + o1]  = rl1;
            *(uint4*)&smem[nxt + 10240 + o0] = sh0;
            *(uint4*)&smem[nxt + 10240 + o1] = sh1;
            *(uint4*)&smem[nxt + 15360 + o0] = sl0;
            *(uint4*)&smem[nxt + 15360 + o1] = sl1;
        }
        __syncthreads();
    }

    bool offdiag = (ti != tj);
    float rs[4][4];
    float cs[4] = {0.f, 0.f, 0.f, 0.f};
#pragma unroll
    for (int i = 0; i < 4; ++i)
#pragma unroll
        for (int r = 0; r < 4; ++r) rs[i][r] = 0.f;

    // exp pass: deg sums + BOTH tile layouts into swizzled LDS
#pragma unroll
    for (int j = 0; j < 4; ++j) {
        int ml = coloff + j * 16 + l16;
        float sm = sqb[m0 + ml];
#pragma unroll
        for (int i = 0; i < 4; ++i) {
#pragma unroll
            for (int r = 0; r < 4; ++r) {
                int nl = rowoff + i * 16 + quad * 4 + r;
                float v = __expf(2.f * acc[i][j][r] - sqb[n0 + nl] - sm);
                rs[i][r] += v;
                ushort_t vb = f2bf(v);
                smem[nl * 128 + (((ml >> 3) ^ (nl & 7)) << 3) + (ml & 7)] = vb;
                if (offdiag) {
                    cs[j] += v;
                    smem[16384 + ml * 128 + (((nl >> 3) ^ (ml & 7)) << 3) + (nl & 7)] = vb;
                }
            }
        }
    }
    __syncthreads();
    // direct tile write, coalesced
    for (int s2 = t; s2 < 2048; s2 += 256) {
        int nl = s2 >> 4, oct = s2 & 15;
        uint4 v4 = *(const uint4*)&smem[nl * 128 + ((oct ^ (nl & 7)) << 3)];
        *(uint4*)(Ab + (size_t)(n0 + nl) * NN + m0 + oct * 8) = v4;
    }

    int slot = tj * 2 + (wave & 1);
#pragma unroll
    for (int i = 0; i < 4; ++i)
#pragma unroll
        for (int r = 0; r < 4; ++r) {
            float s = rs[i][r];
            s += __shfl_xor(s, 1);
            s += __shfl_xor(s, 2);
            s += __shfl_xor(s, 4);
            s += __shfl_xor(s, 8);
            if (l16 == 0)
                deg_part[((size_t)slot * BCv + b) * NN + n0 + rowoff + i * 16 + quad * 4 + r] = s;
        }

    if (offdiag) {
        // column sums -> mirror rows' partials: slot ti*2 + (wave>>1)
#pragma unroll
        for (int j = 0; j < 4; ++j) {
            float s = cs[j];
            s += __shfl_xor(s, 16);
            s += __shfl_xor(s, 32);
            cs[j] = s;
        }
        if (quad == 0) {
#pragma unroll
            for (int j = 0; j < 4; ++j)
                deg_part[((size_t)(ti * 2 + (wave >> 1)) * BCv + b) * NN +
                         m0 + coloff + j * 16 + l16] = cs[j];
        }
        // mirrored tile write, coalesced (layout 2 written pre-sync above)
        for (int s2 = t; s2 < 2048; s2 += 256) {
            int ml = s2 >> 4, oct = s2 & 15;
            uint4 v4 = *(const uint4*)&smem[16384 + ml * 128 + ((oct ^ (ml & 7)) << 3)];
            *(uint4*)(Ab + (size_t)(m0 + ml) * NN + n0 + oct * 8) = v4;
        }
    }
}

// dis[b][n] = rsqrt(sum of 16 deg partials); Xt[b][f][n0..] *= dis[n] in place.
__global__ __launch_bounds__(256) void disscale_kernel(
    ushort_t* __restrict__ Xt, const float* __restrict__ deg_part,
    float* __restrict__ dis, int Fp, int bsh, int BCv) {
    int L = blockIdx.x;
    int b = L & ((1 << bsh) - 1), n0 = (L >> bsh) * 64;
    int t = threadIdx.x;
    __shared__ float dloc[64];
    if (t < 64) {
        float s = 0.f;
#pragma unroll
        for (int k = 0; k < 16; ++k) s += deg_part[((size_t)k * BCv + b) * NN + n0 + t];
        float d = rsqrtf(s);
        dloc[t] = d;
        dis[(size_t)b * NN + n0 + t] = d;
    }
    __syncthreads();
    int lane = t & 63, fq = t >> 6;
    float d = dloc[lane];
    ushort_t* Xb = Xt + (size_t)b * Fp * NN + n0 + lane;
    for (int f = fq; f < Fp; f += 4) {
        size_t off = (size_t)f * NN;
        Xb[off] = f2bf(bf2f(Xb[off]) * d);
    }
}

// lx: acc[f][n] = sum_k in_t[f][k] * A[n][k]  (A raw symmetric).
// Tile 128f x 64n, 4 waves (rowoff=wave*32), acc[2][4], K=1024 in 32 steps.
// gld_lds staging, TRIPLE-buffered (depth-2), raw s_barrier + counted vmcnt(3).
// 36KB LDS -> 4 blocks/CU; grid 2048 = exactly 2 full rounds (no tail).
// mode0: out_t = xin - dn^2*acc; out_b = inv*xin - dn*acc.
// mode1: out_b = inv*(2*xin - x0) - 2*dn*acc.
__global__ __launch_bounds__(256) void lx_kernel(
    const ushort_t* __restrict__ Abf, const float* __restrict__ dis,
    const ushort_t* __restrict__ in_t, const ushort_t* __restrict__ x0t,
    ushort_t* __restrict__ out_t, ushort_t* __restrict__ out_b,
    int F, int Fp, int mode, int ft, int bsh) {
    int t = threadIdx.x;
    int L = blockIdx.x;
    int b = L & ((1 << bsh) - 1);
    int rest = L >> bsh;
    int m0 = (rest % ft) * 128;   // f tile (128)
    int n0 = (rest / ft) * 64;    // n tile (64)
    const ushort_t* Ain = in_t + (size_t)b * Fp * NN;
    const ushort_t* Ab = Abf + (size_t)b * NN * NN;

    int lane = t & 63, quad = lane >> 4, l16 = lane & 15, wave = t >> 6;
    int rowoff = wave * 32;

    __shared__ __align__(16) ushort_t smem[18432];   // 3 x (A[128][32]=4096 + B[64][32]=2048)

    f32x4 acc[2][4];
#pragma unroll
    for (int i = 0; i < 2; ++i)
#pragma unroll
        for (int j = 0; j < 4; ++j) acc[i][j] = (f32x4){0.f, 0.f, 0.f, 0.f};

    int lr = lane >> 2, lk = (lane & 3) * 8;
    int rbase = wave * 32;
    const ushort_t* gA = Ain + (size_t)(m0 + rbase + lr) * NN + lk;
    const ushort_t* gB = Ab + (size_t)(n0 + wave * 16 + lr) * NN + lk;

#define LX_STAGE(BOFF, CI)                                            \
    {                                                                 \
        int k_ = (CI) * 32;                                           \
        ushort_t* As_ = smem + (BOFF);                                \
        gld16(gA + k_, As_ + rbase * 32);                             \
        gld16(gA + (size_t)16 * NN + k_, As_ + rbase * 32 + 512);     \
        gld16(gB + k_, As_ + 4096 + wave * 16 * 32);                  \
    }
#define LX_COMP(BOFF)                                                            \
    {                                                                            \
        ushort_t* As_ = smem + (BOFF);                                           \
        ushort_t* Bs_ = As_ + 4096;                                              \
        bf16x8 af[2], bfv[4];                                                    \
        _Pragma("unroll")                                                        \
        for (int i = 0; i < 2; ++i)                                              \
            af[i] = *(const bf16x8*)&As_[(rowoff + i * 16 + l16) * 32 + quad * 8]; \
        _Pragma("unroll")                                                        \
        for (int j = 0; j < 4; ++j)                                              \
            bfv[j] = *(const bf16x8*)&Bs_[(j * 16 + l16) * 32 + quad * 8];       \
        _Pragma("unroll")                                                        \
        for (int i = 0; i < 2; ++i)                                              \
            _Pragma("unroll")                                                    \
            for (int j = 0; j < 4; ++j)                                          \
                acc[i][j] = __builtin_amdgcn_mfma_f32_16x16x32_bf16(af[i], bfv[j], acc[i][j], 0, 0, 0); \
    }

    LX_STAGE(0, 0);
    LX_STAGE(6144, 1);
    int cur = 0;
    for (int ci = 0; ci < 32; ++ci) {
        if (ci < 31) { asm volatile("s_waitcnt vmcnt(3)" ::: "memory"); }
        else         { asm volatile("s_waitcnt vmcnt(0)" ::: "memory"); }
        __builtin_amdgcn_s_barrier();
        asm volatile("" ::: "memory");
        if (ci + 2 < 32) {
            int noff = cur + 12288; if (noff >= 18432) noff -= 18432;
            LX_STAGE(noff, ci + 2);
        }
        LX_COMP(cur);
        cur += 6144; if (cur >= 18432) cur = 0;
    }
#undef LX_STAGE
#undef LX_COMP
    __syncthreads();   // all waves done reading stage bufs before epilogue reuse

#pragma unroll
    for (int j = 0; j < 4; ++j) {
        int nl = j * 16 + l16;
        int n = n0 + nl;
        float dn = dis[(size_t)b * NN + n];
        float inv = 1.f / dn;
        float dn2 = dn * dn;
#pragma unroll
        for (int i = 0; i < 2; ++i) {
#pragma unroll
            for (int r = 0; r < 4; ++r) {
                int fl = rowoff + i * 16 + quad * 4 + r;
                int f = m0 + fl;
                float o = 0.f;
                if (f < F) {
                    float a = acc[i][j][r];
                    size_t off = (size_t)f * NN + n;
                    float xin = bf2f(Ain[off]);
                    if (mode == 0) {
                        out_t[(size_t)b * Fp * NN + off] = f2bf(xin - dn2 * a);
                        o = inv * xin - dn * a;
                    } else {
                        float x0 = bf2f(x0t[(size_t)b * Fp * NN + off]);
                        o = inv * (2.f * xin - x0) - 2.f * dn * a;
                    }
                }
                smem[nl * 128 + (((fl >> 3) ^ (nl & 7)) << 3) + (fl & 7)] = f2bf(o);
            }
        }
    }
    __syncthreads();
    for (int s2 = t; s2 < 1024; s2 += 256) {
        int nl = s2 >> 4, oct = s2 & 15;
        int fg = m0 + oct * 8;
        if (fg < Fp) {
            uint4 v = *(const uint4*)&smem[nl * 128 + ((oct ^ (nl & 7)) << 3)];
            *(uint4*)(out_b + ((size_t)b * NN + n0 + nl) * Fp + fg) = v;
        }
    }
}

// Out[r][g] = relu( sum_p Xp[r][:].Wt[p][g][:] + bias[g] ).
// 256r x 128g tile, 8 waves (512 thr, 4x2 of 64x64 each), gld_lds staging,
// TRIPLE-buffered (depth-2), counted vmcnt(3).
// Ohi/Olo != null: write hi/lo bf16 split (next layer's adj input format).
// Ohi == null (layer3): fused maxpool. 1D grid n_g*4*BC.
__global__ __launch_bounds__(512) void proj_kernel(
    const ushort_t* __restrict__ X0, const ushort_t* __restrict__ X1,
    const ushort_t* __restrict__ X2, const ushort_t* __restrict__ Wt,
    const float* __restrict__ bias, ushort_t* __restrict__ Ohi,
    ushort_t* __restrict__ Olo, float* __restrict__ pool,
    int Fp, int Fo, int b0, int n_g, int bsh) {
    int t = threadIdx.x;
    int L = blockIdx.x;
    int c = L & ((1 << bsh) - 1);
    int rest = L >> bsh;
    int g0 = (rest % n_g) * 128;
    int r0 = (c * 4 + rest / n_g) * 256;
    int lane = t & 63, quad = lane >> 4, l16 = lane & 15, wave = t >> 6;
    int rowoff = (wave >> 1) * 64, coloff = (wave & 1) * 64;

    __shared__ __align__(16) ushort_t smem[36864];   // 3 x (A[256][32] + B[128][32])

    f32x4 acc[4][4];
#pragma unroll
    for (int i = 0; i < 4; ++i)
#pragma unroll
        for (int j = 0; j < 4; ++j) acc[i][j] = (f32x4){0.f, 0.f, 0.f, 0.f};

    int lr = lane >> 2, lk = (lane & 3) * 8;
    int nk = Fp >> 5;
    int NIT = 3 * nk;
    size_t FoFp = (size_t)Fo * Fp;
    size_t r16 = (size_t)16 * Fp;

#define PJ_STAGE(BOFF, CI)                                                    \
    {                                                                         \
        int p_ = (CI) / nk;                                                   \
        int k_ = ((CI) - p_ * nk) * 32 + lk;                                  \
        const ushort_t* Xp_ = (p_ == 0) ? X0 : ((p_ == 1) ? X1 : X2);         \
        const ushort_t* ga_ = Xp_ + (size_t)(r0 + wave * 32 + lr) * Fp + k_;  \
        const ushort_t* gb_ = Wt + (size_t)p_ * FoFp +                        \
                              (size_t)(g0 + wave * 16 + lr) * Fp + k_;        \
        ushort_t* As_ = smem + (BOFF) + wave * 1024;                          \
        ushort_t* Bs_ = smem + (BOFF) + 8192 + wave * 512;                    \
        gld16(ga_, As_);                                                      \
        gld16(ga_ + r16, As_ + 512);                                          \
        gld16(gb_, Bs_);                                                      \
    }
#define PJ_COMP(BOFF)                                                           \
    {                                                                           \
        ushort_t* As_ = smem + (BOFF);                                          \
        ushort_t* Bs_ = As_ + 8192;                                             \
        bf16x8 af[4], bfv[4];                                                   \
        _Pragma("unroll")                                                       \
        for (int i = 0; i < 4; ++i)                                             \
            af[i] = *(const bf16x8*)&As_[(rowoff + i * 16 + l16) * 32 + quad * 8];  \
        _Pragma("unroll")                                                       \
        for (int j = 0; j < 4; ++j)                                             \
            bfv[j] = *(const bf16x8*)&Bs_[(coloff + j * 16 + l16) * 32 + quad * 8]; \
        _Pragma("unroll")                                                       \
        for (int i = 0; i < 4; ++i)                                             \
            _Pragma("unroll")                                                   \
            for (int j = 0; j < 4; ++j)                                         \
                acc[i][j] = __builtin_amdgcn_mfma_f32_16x16x32_bf16(af[i], bfv[j], acc[i][j], 0, 0, 0); \
    }

    PJ_STAGE(0, 0);
    PJ_STAGE(12288, 1);
    int cur = 0;
    for (int ci = 0; ci < NIT; ++ci) {
        if (ci < NIT - 1) { asm volatile("s_waitcnt vmcnt(3)" ::: "memory"); }
        else              { asm volatile("s_waitcnt vmcnt(0)" ::: "memory"); }
        __builtin_amdgcn_s_barrier();
        asm volatile("" ::: "memory");
        if (ci + 2 < NIT) {
            int noff = cur + 24576; if (noff >= 36864) noff -= 36864;
            PJ_STAGE(noff, ci + 2);
        }
        PJ_COMP(cur);
        cur += 12288; if (cur >= 36864) cur = 0;
    }
#undef PJ_STAGE
#undef PJ_COMP

    float bias_l[4];
#pragma unroll
    for (int j = 0; j < 4; ++j) bias_l[j] = bias[g0 + coloff + j * 16 + l16];

    if (Ohi) {
#pragma unroll
        for (int i = 0; i < 4; ++i) {
#pragma unroll
            for (int r = 0; r < 4; ++r) {
                int row = r0 + rowoff + i * 16 + quad * 4 + r;
#pragma unroll
                for (int j = 0; j < 4; ++j) {
                    int g = g0 + coloff + j * 16 + l16;
                    float o = fmaxf(acc[i][j][r] + bias_l[j], 0.f);
                    ushort_t h = f2bf(o);
                    size_t off = (size_t)row * Fo + g;
                    Ohi[off] = h;
                    Olo[off] = f2bf(o - bf2f(h));
                }
            }
        }
    } else {
        float mj[4];
#pragma unroll
        for (int j = 0; j < 4; ++j) {
            float m = 0.f;
#pragma unroll
            for (int i = 0; i < 4; ++i)
#pragma unroll
                for (int r = 0; r < 4; ++r)
                    m = fmaxf(m, acc[i][j][r] + bias_l[j]);
            m = fmaxf(m, 0.f);
            m = fmaxf(m, __shfl_xor(m, 16));
            m = fmaxf(m, __shfl_xor(m, 32));
            mj[j] = m;
        }
        if (quad == 0) {
            int smp = b0 + (r0 >> 10);
#pragma unroll
            for (int j = 0; j < 4; ++j)
                atomicMax((int*)&pool[(size_t)smp * 1024 + g0 + coloff + j * 16 + l16],
                          __float_as_int(mj[j]));
        }
    }
}

// fc: block = (row, 64-col tile); 4 K-slices x 64 cols; LDS reduce.
__global__ __launch_bounds__(256) void fc_kernel(
    const float* __restrict__ In, const float* __restrict__ W,
    const float* __restrict__ bias, float* __restrict__ out,
    int K, int Nout, int relu) {
    int r = blockIdx.y;
    int c0 = blockIdx.x * 64;
    int t = threadIdx.x;
    int cl = t & 63, ks = t >> 6;
    int c = c0 + cl;
    int kchunk = K >> 2;
    int k0 = ks * kchunk, k1 = k0 + kchunk;
    float s = 0.f;
    if (c < Nout) {
        const float* ip = In + (size_t)r * K;
        const float* wp = W + c;
#pragma unroll 4
        for (int k = k0; k < k1; ++k) s += ip[k] * wp[(size_t)k * Nout];
    }
    __shared__ float red[4][64];
    red[ks][cl] = s;
    __syncthreads();
    if (t < 64 && c0 + t < Nout) {
        float v = red[0][t] + red[1][t] + red[2][t] + red[3][t] + bias[c0 + t];
        if (relu) v = fmaxf(v, 0.f);
        out[(size_t)r * Nout + c0 + t] = v;
    }
}

// ---------------------------------------------------------------------------
extern "C" void kernel_launch(void* const* d_in, const int* in_sizes, int n_in,
                              void* d_out, int out_size, void* d_ws, size_t ws_size,
                              hipStream_t stream) {
    const float* x    = (const float*)d_in[0];
    const float* W1   = (const float*)d_in[1];
    const float* b1   = (const float*)d_in[2];
    const float* W2   = (const float*)d_in[3];
    const float* b2   = (const float*)d_in[4];
    const float* W3   = (const float*)d_in[5];
    const float* b3   = (const float*)d_in[6];
    const float* fc1w = (const float*)d_in[7];
    const float* fc1b = (const float*)d_in[8];
    const float* fc2w = (const float*)d_in[9];
    const float* fc2b = (const float*)d_in[10];
    const float* fc3w = (const float*)d_in[11];
    const float* fc3b = (const float*)d_in[12];
    float* out = (float*)d_out;

    // Abf + 5 rotating slots + Wt + sq/degp/dis + pool/f1/f2
    auto need = [](size_t BCv) -> size_t {
        size_t us = (size_t)BCv * 1024;
        return 2 * (us * 1024) + 10 * (us * 512) + 2 * 1781760ull +
               4 * us + 64 * us + 4 * us +
               4 * (32768ull + 16384 + 4096) + 256;
    };
    int BCv = (ws_size >= need(32)) ? 32 : (ws_size >= need(16)) ? 16 : 8;
    int NCH = 32 / BCv;
    int bsh = (BCv == 32) ? 5 : (BCv == 16) ? 4 : 3;

    size_t usc = (size_t)BCv * 1024;
    size_t Asz = usc * 1024;           // ushorts
    size_t SLv = usc * 512;            // ushorts
    ushort_t* Abf = (ushort_t*)d_ws;
    ushort_t* S[5];
    S[0] = Abf + Asz;
    for (int i = 1; i < 5; ++i) S[i] = S[i - 1] + SLv;
    ushort_t* Wt = S[4] + SLv;         // 1781760 ushorts
    float* sq   = (float*)(Wt + 1781760);
    float* degp = sq + usc;            // 16*BC*NN
    float* dis  = degp + 16 * usc;     // BC*NN
    float* pool = dis + usc;           // 32*1024
    float* f1   = pool + 32768;
    float* f2   = f1 + 16384;

    init_kernel<<<454, 256, 0, stream>>>(W1, W2, W3, Wt, pool);

    // slot roles per layer: xhi, xlo(=X2b), Xt, X1t, X1b; liveness-verified rotation
    const int MP[3][5] = {{0, 1, 2, 3, 4}, {3, 2, 0, 4, 1}, {4, 0, 3, 1, 2}};

    for (int c = 0; c < NCH; ++c) {
        int b0 = c * BCv;
        struct LayerDef {
            int F, Fp, Fo;
            const ushort_t* Wtl; const float* bias;
        };
        LayerDef L[3] = {
            { 6,   32,  128,  Wt,          b1 },
            { 128, 128, 512,  Wt + 12288,  b2 },
            { 512, 512, 1024, Wt + 208896, b3 },
        };
        for (int li = 0; li < 3; ++li) {
            LayerDef& Ld = L[li];
            int F = Ld.F, Fp = Ld.Fp;
            int ft = (F + 127) / 128;
            int n_g = Ld.Fo / 128;
            ushort_t* xhi = S[MP[li][0]];
            ushort_t* xlo = S[MP[li][1]];
            ushort_t* Xt  = S[MP[li][2]];
            ushort_t* X1t = S[MP[li][3]];
            ushort_t* X1b = S[MP[li][4]];
            prep2_kernel<<<16 * BCv, 256, 0, stream>>>(
                (li == 0) ? (x + (size_t)b0 * NN * 6) : nullptr,
                xhi, xlo, Xt, sq, F, Fp, bsh);
            adj_kernel<<<36 * BCv, 256, 0, stream>>>(xhi, xlo, sq, Abf, degp, Fp, bsh, BCv);
            disscale_kernel<<<16 * BCv, 256, 0, stream>>>(Xt, degp, dis, Fp, bsh, BCv);
            lx_kernel<<<ft * 16 * BCv, 256, 0, stream>>>(
                Abf, dis, Xt, nullptr, X1t, X1b, F, Fp, 0, ft, bsh);
            lx_kernel<<<ft * 16 * BCv, 256, 0, stream>>>(
                Abf, dis, X1t, Xt, nullptr, xlo, F, Fp, 1, ft, bsh);
            // next layer's xhi = this X1t slot, xlo = this Xt slot (both dead here)
            proj_kernel<<<n_g * 4 * BCv, 512, 0, stream>>>(
                xhi, X1b, xlo, Ld.Wtl, Ld.bias,
                (li < 2) ? X1t : nullptr, (li < 2) ? Xt : nullptr,
                pool, Fp, Ld.Fo, b0, n_g, bsh);
        }
    }

    fc_kernel<<<dim3(8, 32), 256, 0, stream>>>(pool, fc1w, fc1b, f1, 1024, 512, 1);
    fc_kernel<<<dim3(2, 32), 256, 0, stream>>>(f1, fc2w, fc2b, f2, 512, 128, 1);
    fc_kernel<<<dim3(1, 32), 256, 0, stream>>>(f2, fc3w, fc3b, out, 128, 40, 0);
}